// Round 1
// baseline (6341.105 us; speedup 1.0000x reference)
//
#include <hip/hip_runtime.h>
#include <hip/hip_bf16.h>

#define IMG 256
#define NPOS 65536

__device__ __forceinline__ float gelu_exact(float x){
  return 0.5f * x * (1.0f + erff(x * 0.7071067811865475f));
}

template<int NWAVES>
__device__ __forceinline__ void block_reduce2(float& s, float& s2, float* red){
  __syncthreads();  // protect red[] reuse from previous call
  #pragma unroll
  for (int off=32; off>0; off>>=1){ s += __shfl_down(s, off); s2 += __shfl_down(s2, off); }
  int lane = threadIdx.x & 63, w = threadIdx.x >> 6;
  if (lane==0){ red[w*2]=s; red[w*2+1]=s2; }
  __syncthreads();
  if (threadIdx.x==0){
    float a=0.f, bb=0.f;
    #pragma unroll
    for (int i=0;i<NWAVES;i++){ a+=red[i*2]; bb+=red[i*2+1]; }
    red[2*NWAVES]=a; red[2*NWAVES+1]=bb;
  }
  __syncthreads();
  s=red[2*NWAVES]; s2=red[2*NWAVES+1];
}

// ---------------- K1: per-window norm1 + CPE + qkv + channel-attention ----------------
// grid 2048 (one block per 8x8 window), 512 threads, dynamic LDS ~142.4 KB
__global__ __launch_bounds__(512) void k1_attn(
    const float* __restrict__ y,
    const float* __restrict__ n1w, const float* __restrict__ n1b,
    const float* __restrict__ cw,  const float* __restrict__ cb,
    const float* __restrict__ cnw, const float* __restrict__ cnb,
    const float* __restrict__ qw,  const float* __restrict__ qb,
    const float* __restrict__ kw,  const float* __restrict__ kb,
    const float* __restrict__ vw,  const float* __restrict__ vb,
    float* __restrict__ out)
{
  extern __shared__ unsigned char smem[];
  __hip_bfloat16* yn = (__hip_bfloat16*)smem;            // 768*64 bf16 = 98304 B
  float* bufA = (float*)(smem + 98304);                  // phase1: 64*64 f32
  float* qs   = (float*)(smem + 98304);                  // phase2: 48*66 f32
  float* ks   = qs + 48*66;
  float* vs   = ks + 48*66;
  float* Sb   = vs + 48*66;                              // 48*49 f32
  float* red  = (float*)(smem + 145728);                 // 18 f32

  const int t  = threadIdx.x;
  const int wi = blockIdx.x;
  const int b  = wi >> 10;
  const int W1 = (wi >> 5) & 31;
  const int W2 = wi & 31;
  const size_t ybase = (size_t)b*768*(size_t)NPOS + (size_t)(W1*8)*IMG + (W2*8);

  // ---- Phase 1: per-group norm1 + CPE -> yn (bf16) ----
  for (int g=0; g<12; ++g){
    float vals[8];
    float s=0.f, s2=0.f;
    #pragma unroll
    for (int kk=0;kk<8;kk++){
      int idx = kk*512 + t;
      int ch = idx >> 6, sp = idx & 63;
      float v = y[ybase + (size_t)(g*64+ch)*NPOS + (sp>>3)*IMG + (sp&7)];
      vals[kk]=v; s+=v; s2+=v*v;
    }
    block_reduce2<8>(s,s2,red);
    float mean = s * (1.f/4096.f);
    float rstd = rsqrtf(s2*(1.f/4096.f) - mean*mean + 1e-5f);
    #pragma unroll
    for (int kk=0;kk<8;kk++){
      int idx = kk*512 + t;
      int ch = idx >> 6;
      int c = g*64+ch;
      bufA[idx] = (vals[kk]-mean)*rstd*n1w[c] + n1b[c];
    }
    __syncthreads();
    // depthwise 3x3, zero-pad at window edges
    float cvals[8]; s=0.f; s2=0.f;
    #pragma unroll
    for (int kk=0;kk<8;kk++){
      int idx = kk*512 + t;
      int ch = idx >> 6, sp = idx & 63;
      int p1 = sp>>3, p2 = sp&7;
      int c = g*64+ch;
      const float* wp = cw + c*9;
      float acc = cb[c];
      #pragma unroll
      for (int dy=0;dy<3;dy++){
        int yy = p1+dy-1;
        if (yy>=0 && yy<8){
          #pragma unroll
          for (int dx=0;dx<3;dx++){
            int xx = p2+dx-1;
            if (xx>=0 && xx<8) acc = fmaf(wp[dy*3+dx], bufA[ch*64 + yy*8+xx], acc);
          }
        }
      }
      cvals[kk]=acc; s+=acc; s2+=acc*acc;
    }
    block_reduce2<8>(s,s2,red);
    mean = s*(1.f/4096.f);
    rstd = rsqrtf(s2*(1.f/4096.f) - mean*mean + 1e-5f);
    #pragma unroll
    for (int kk=0;kk<8;kk++){
      int idx = kk*512+t;
      int ch = idx>>6, sp = idx&63;
      int c = g*64+ch;
      float f = (cvals[kk]-mean)*rstd*cnw[c] + cnb[c];
      float v = bufA[idx] + gelu_exact(f);
      yn[(g*64+ch)*64 + sp] = __float2bfloat16(v);
    }
    __syncthreads();  // bufA reused next group / phase 2
  }

  // ---- Phase 2: per-head qkv + attention ----
  const int n    = t & 63;
  const int u    = t >> 6;        // 0..7
  const int ublk = u >> 1;        // 0..3 -> groups 3*ublk..3*ublk+2
  const int rbase= (u & 1)*2;     // 0 or 2
  const float scale = 0.14433756729740643f;  // 48^-0.5

  for (int h=0; h<16; ++h){
    // Step A: q,k,v for this head (channels c = d*16+h), d = 4g+r
    #pragma unroll 1
    for (int gg=0; gg<3; ++gg){
      int g = ublk*3 + gg;
      int c0 = (4*g+rbase+0)*16 + h;
      int c1 = (4*g+rbase+1)*16 + h;
      const float* qw0 = qw + c0*64; const float* qw1 = qw + c1*64;
      const float* kw0 = kw + c0*64; const float* kw1 = kw + c1*64;
      const float* vw0 = vw + c0*64; const float* vw1 = vw + c1*64;
      const __hip_bfloat16* ynp = yn + g*4096 + n;
      float aq0=0,aq1=0,ak0=0,ak1=0,av0=0,av1=0;
      #pragma unroll 4
      for (int i=0;i<64;i++){
        float yv = __bfloat162float(ynp[(size_t)i*64]);
        aq0 = fmaf(qw0[i], yv, aq0); aq1 = fmaf(qw1[i], yv, aq1);
        ak0 = fmaf(kw0[i], yv, ak0); ak1 = fmaf(kw1[i], yv, ak1);
        av0 = fmaf(vw0[i], yv, av0); av1 = fmaf(vw1[i], yv, av1);
      }
      int d0 = 4*g+rbase;
      qs[(d0+0)*66+n] = (aq0 + qb[c0]) * scale;
      qs[(d0+1)*66+n] = (aq1 + qb[c1]) * scale;
      ks[(d0+0)*66+n] = ak0 + kb[c0];
      ks[(d0+1)*66+n] = ak1 + kb[c1];
      vs[(d0+0)*66+n] = av0 + vb[c0];
      vs[(d0+1)*66+n] = av1 + vb[c1];
    }
    __syncthreads();
    // Step B: S = q k^T  (48x48, K=64), 16x16 thread grid of 3x3 tiles
    if (t < 256){
      int d0 = (t >> 4)*3, e0 = (t & 15)*3;
      float acc[3][3] = {{0,0,0},{0,0,0},{0,0,0}};
      #pragma unroll 4
      for (int i=0;i<64;i++){
        float qv0=qs[(d0+0)*66+i], qv1=qs[(d0+1)*66+i], qv2=qs[(d0+2)*66+i];
        float kv0=ks[(e0+0)*66+i], kv1=ks[(e0+1)*66+i], kv2=ks[(e0+2)*66+i];
        acc[0][0]=fmaf(qv0,kv0,acc[0][0]); acc[0][1]=fmaf(qv0,kv1,acc[0][1]); acc[0][2]=fmaf(qv0,kv2,acc[0][2]);
        acc[1][0]=fmaf(qv1,kv0,acc[1][0]); acc[1][1]=fmaf(qv1,kv1,acc[1][1]); acc[1][2]=fmaf(qv1,kv2,acc[1][2]);
        acc[2][0]=fmaf(qv2,kv0,acc[2][0]); acc[2][1]=fmaf(qv2,kv1,acc[2][1]); acc[2][2]=fmaf(qv2,kv2,acc[2][2]);
      }
      #pragma unroll
      for (int a=0;a<3;a++)
        #pragma unroll
        for (int e=0;e<3;e++)
          Sb[(d0+a)*49 + (e0+e)] = acc[a][e];
    }
    __syncthreads();
    // masked softmax per row (block-causal: e//4 <= d//4  <=>  e <= d|3)
    if (t < 48){
      int d = t; int emax = d | 3;
      float m = -1e30f;
      for (int e=0;e<=emax;e++) m = fmaxf(m, Sb[d*49+e]);
      float ssum = 0.f;
      for (int e=0;e<=emax;e++){ float p = expf(Sb[d*49+e]-m); Sb[d*49+e]=p; ssum+=p; }
      float inv = 1.f/ssum;
      for (int e=0;e<=emax;e++) Sb[d*49+e] *= inv;
      for (int e=emax+1;e<48;e++) Sb[d*49+e] = 0.f;
    }
    __syncthreads();
    // Step C: out = P @ v ; thread (n, u) handles d = u*6..u*6+5
    {
      float acc[6] = {0,0,0,0,0,0};
      int dbase = u*6;
      for (int e=0;e<48;e++){
        float vv = vs[e*66+n];
        #pragma unroll
        for (int dd=0;dd<6;dd++)
          acc[dd] = fmaf(Sb[(dbase+dd)*49+e], vv, acc[dd]);
      }
      #pragma unroll
      for (int dd=0;dd<6;dd++){
        int c = (dbase+dd)*16 + h;   // channel = d*HEADS + h
        out[ybase + (size_t)c*NPOS + (n>>3)*IMG + (n&7)] = acc[dd];
      }
    }
    __syncthreads();  // qs/ks/vs/Sb reused next head
  }
}

// ---------------- K2: grouped proj + residual (in-place on d_out) + norm2 partials ----
__global__ __launch_bounds__(256) void k2_proj(
    const float* __restrict__ y,
    const float* __restrict__ pw, const float* __restrict__ pb,
    float* __restrict__ io, float* __restrict__ part)
{
  const int t = threadIdx.x;
  const int tile = blockIdx.x;   // 0..255
  const int g = blockIdx.y;      // 0..11
  const int b = blockIdx.z;      // 0..1
  const int pos = tile*256 + t;
  const size_t base = ((size_t)(b*768 + g*64))*NPOS + pos;
  float x[64];
  #pragma unroll
  for (int i=0;i<64;i++) x[i] = io[base + (size_t)i*NPOS];
  float s=0.f, s2=0.f;
  for (int cp=0; cp<64; ++cp){
    const float* wr = pw + (g*64+cp)*64;
    float a0=0,a1=0,a2=0,a3=0;
    #pragma unroll
    for (int i=0;i<64;i+=4){
      a0 = fmaf(wr[i+0], x[i+0], a0);
      a1 = fmaf(wr[i+1], x[i+1], a1);
      a2 = fmaf(wr[i+2], x[i+2], a2);
      a3 = fmaf(wr[i+3], x[i+3], a3);
    }
    float o = y[base + (size_t)cp*NPOS] + pb[g*64+cp] + ((a0+a1)+(a2+a3));
    io[base + (size_t)cp*NPOS] = o;
    s += o; s2 += o*o;
  }
  __shared__ float red[10];
  block_reduce2<4>(s,s2,red);
  if (t==0){
    int bg = b*12+g;
    part[(size_t)(bg*256+tile)*2+0] = s;
    part[(size_t)(bg*256+tile)*2+1] = s2;
  }
}

// ---------------- K3: finalize norm2 stats (deterministic) ----------------
__global__ __launch_bounds__(256) void k3_stats(
    const float* __restrict__ part, float* __restrict__ stats)
{
  const int bg = blockIdx.x;  // 0..23
  const int t = threadIdx.x;
  float s  = part[(size_t)(bg*256+t)*2+0];
  float s2 = part[(size_t)(bg*256+t)*2+1];
  __shared__ float red[10];
  block_reduce2<4>(s,s2,red);
  if (t==0){
    const float Ninv = 1.f/(64.f*65536.f);
    float mean = s*Ninv;
    float var  = s2*Ninv - mean*mean;
    stats[bg*2+0] = mean;
    stats[bg*2+1] = rsqrtf(var + 1e-5f);
  }
}

// ---------------- K4: norm2 + f1 + gelu + f2 + residual (in-place) ----------------
__global__ __launch_bounds__(256) void k4_mlp(
    const float* __restrict__ n2w, const float* __restrict__ n2b,
    const float* __restrict__ f1w, const float* __restrict__ f1b,
    const float* __restrict__ f2w, const float* __restrict__ f2b,
    const float* __restrict__ stats,
    float* __restrict__ io)
{
  __shared__ float hl[64*256];   // h staged via LDS (avoid runtime-indexed reg array)
  const int t = threadIdx.x;
  const int tile = blockIdx.x;
  const int g = blockIdx.y;
  const int b = blockIdx.z;
  const int pos = tile*256 + t;
  const int bg = b*12+g;
  const float mean = stats[bg*2+0], rstd = stats[bg*2+1];
  const size_t base = ((size_t)(b*768 + g*64))*NPOS + pos;
  float xn[64];
  #pragma unroll
  for (int i=0;i<64;i++){
    float v = io[base + (size_t)i*NPOS];
    xn[i] = (v-mean)*rstd*n2w[g*64+i] + n2b[g*64+i];
  }
  for (int cp=0; cp<64; ++cp){
    const float* wr = f1w + (g*64+cp)*64;
    float a0=0,a1=0,a2=0,a3=0;
    #pragma unroll
    for (int i=0;i<64;i+=4){
      a0 = fmaf(wr[i+0], xn[i+0], a0);
      a1 = fmaf(wr[i+1], xn[i+1], a1);
      a2 = fmaf(wr[i+2], xn[i+2], a2);
      a3 = fmaf(wr[i+3], xn[i+3], a3);
    }
    hl[cp*256+t] = gelu_exact(f1b[g*64+cp] + ((a0+a1)+(a2+a3)));
  }
  float hr[64];
  #pragma unroll
  for (int i=0;i<64;i++) hr[i] = hl[i*256+t];
  for (int cp=0; cp<64; ++cp){
    const float* wr = f2w + (g*64+cp)*64;
    float a0=0,a1=0,a2=0,a3=0;
    #pragma unroll
    for (int i=0;i<64;i+=4){
      a0 = fmaf(wr[i+0], hr[i+0], a0);
      a1 = fmaf(wr[i+1], hr[i+1], a1);
      a2 = fmaf(wr[i+2], hr[i+2], a2);
      a3 = fmaf(wr[i+3], hr[i+3], a3);
    }
    float o = io[base + (size_t)cp*NPOS] + f2b[g*64+cp] + ((a0+a1)+(a2+a3));
    io[base + (size_t)cp*NPOS] = o;
  }
}

extern "C" void kernel_launch(void* const* d_in, const int* in_sizes, int n_in,
                              void* d_out, int out_size, void* d_ws, size_t ws_size,
                              hipStream_t stream){
  const float* y    = (const float*)d_in[0];
  const float* n1w  = (const float*)d_in[1];
  const float* n1b  = (const float*)d_in[2];
  const float* cw   = (const float*)d_in[3];
  const float* cb   = (const float*)d_in[4];
  const float* cnw  = (const float*)d_in[5];
  const float* cnb  = (const float*)d_in[6];
  const float* qw   = (const float*)d_in[7];
  const float* qb   = (const float*)d_in[8];
  const float* kw   = (const float*)d_in[9];
  const float* kb   = (const float*)d_in[10];
  const float* vw   = (const float*)d_in[11];
  const float* vb   = (const float*)d_in[12];
  const float* pw   = (const float*)d_in[13];
  const float* pb   = (const float*)d_in[14];
  const float* n2w  = (const float*)d_in[15];
  const float* n2b  = (const float*)d_in[16];
  const float* f1w  = (const float*)d_in[17];
  const float* f1b  = (const float*)d_in[18];
  const float* f2w  = (const float*)d_in[19];
  const float* f2b  = (const float*)d_in[20];
  float* out   = (float*)d_out;
  float* part  = (float*)d_ws;                 // 24*256*2 f32 = 48 KB
  float* stats = part + 24*256*2;              // 48 f32

  const size_t lds1 = 145728 + 18*4;           // ~142.4 KB dynamic LDS
  hipLaunchKernelGGL(k1_attn, dim3(2048), dim3(512), lds1, stream,
                     y, n1w,n1b, cw,cb, cnw,cnb, qw,qb, kw,kb, vw,vb, out);
  hipLaunchKernelGGL(k2_proj, dim3(256,12,2), dim3(256), 0, stream, y, pw, pb, out, part);
  hipLaunchKernelGGL(k3_stats, dim3(24), dim3(256), 0, stream, part, stats);
  hipLaunchKernelGGL(k4_mlp, dim3(256,12,2), dim3(256), 0, stream,
                     n2w,n2b, f1w,f1b, f2w,f2b, stats, out);
}

// Round 2
// 4039.924 us; speedup vs baseline: 1.5696x; 1.5696x over previous
//
#include <hip/hip_runtime.h>
#include <hip/hip_bf16.h>

#define IMG 256
#define NPOS 65536

typedef __attribute__((ext_vector_type(8))) short short8;
typedef __attribute__((ext_vector_type(4))) float f32x4;

// LDS byte offsets (phase 2)
#define YNT_PITCH 1552          // 776 bf16 per row (position-major, channel cols)
#define QO 99328                // q bf16 [2][48][72]
#define KO 113152               // k bf16 [2][48][72]
#define VO 126976               // vT bf16 [2][64][72] (col=e, rows=n), e 48..63 zeroed
#define SO 145408               // S f32 [48][52]
#define PO 155392               // P bf16 [48][72]
#define REDO 162304             // red f32[32]
#define LDS_TOTAL 162432

__device__ __forceinline__ float gelu_exact(float x){
  return 0.5f * x * (1.0f + erff(x * 0.7071067811865475f));
}

__device__ __forceinline__ short f2b(float x){
  __hip_bfloat16 h = __float2bfloat16(x);
  short s;
  __builtin_memcpy(&s, &h, sizeof(s));
  return s;
}

template<int NWAVES>
__device__ __forceinline__ void block_reduce2(float& s, float& s2, float* red){
  __syncthreads();  // protect red[] reuse from previous call
  #pragma unroll
  for (int off=32; off>0; off>>=1){ s += __shfl_down(s, off); s2 += __shfl_down(s2, off); }
  int lane = threadIdx.x & 63, w = threadIdx.x >> 6;
  if (lane==0){ red[w*2]=s; red[w*2+1]=s2; }
  __syncthreads();
  if (threadIdx.x==0){
    float a=0.f, bb=0.f;
    #pragma unroll
    for (int i=0;i<NWAVES;i++){ a+=red[i*2]; bb+=red[i*2+1]; }
    red[2*NWAVES]=a; red[2*NWAVES+1]=bb;
  }
  __syncthreads();
  s=red[2*NWAVES]; s2=red[2*NWAVES+1];
}

// ---------------- K1: per-window norm1 + CPE + MFMA qkv + channel-attention ----------------
// grid 2048 (one block per 8x8 window), 512 threads, dynamic LDS 162432 B
__global__ __launch_bounds__(512) void k1_attn(
    const float* __restrict__ y,
    const float* __restrict__ n1w, const float* __restrict__ n1b,
    const float* __restrict__ cw,  const float* __restrict__ cb,
    const float* __restrict__ cnw, const float* __restrict__ cnb,
    const float* __restrict__ qw,  const float* __restrict__ qb,
    const float* __restrict__ kw,  const float* __restrict__ kb,
    const float* __restrict__ vw,  const float* __restrict__ vb,
    float* __restrict__ out)
{
  extern __shared__ unsigned char smem[];
  float* bufA = (float*)(smem + QO);       // phase1 scratch: 64*64 f32 (overlaps q/k region)
  float* red  = (float*)(smem + REDO);

  const int t  = threadIdx.x;
  const int wi = blockIdx.x;
  const int b  = wi >> 10;
  const int W1 = (wi >> 5) & 31;
  const int W2 = wi & 31;
  const size_t ybase = (size_t)b*768*(size_t)NPOS + (size_t)(W1*8)*IMG + (W2*8);

  // ---- Phase 1: per-group norm1 + CPE -> ynT (bf16, transposed [n][c]) ----
  for (int g=0; g<12; ++g){
    float vals[8];
    float s=0.f, s2=0.f;
    #pragma unroll
    for (int kk=0;kk<8;kk++){
      int idx = kk*512 + t;
      int ch = idx >> 6, sp = idx & 63;
      float v = y[ybase + (size_t)(g*64+ch)*NPOS + (sp>>3)*IMG + (sp&7)];
      vals[kk]=v; s+=v; s2+=v*v;
    }
    block_reduce2<8>(s,s2,red);
    float mean = s * (1.f/4096.f);
    float rstd = rsqrtf(s2*(1.f/4096.f) - mean*mean + 1e-5f);
    #pragma unroll
    for (int kk=0;kk<8;kk++){
      int idx = kk*512 + t;
      int ch = idx >> 6;
      int c = g*64+ch;
      bufA[idx] = (vals[kk]-mean)*rstd*n1w[c] + n1b[c];
    }
    __syncthreads();
    // depthwise 3x3, zero-pad at window edges
    float cvals[8]; s=0.f; s2=0.f;
    #pragma unroll
    for (int kk=0;kk<8;kk++){
      int idx = kk*512 + t;
      int ch = idx >> 6, sp = idx & 63;
      int p1 = sp>>3, p2 = sp&7;
      int c = g*64+ch;
      const float* wp = cw + c*9;
      float acc = cb[c];
      #pragma unroll
      for (int dy=0;dy<3;dy++){
        int yy = p1+dy-1;
        if (yy>=0 && yy<8){
          #pragma unroll
          for (int dx=0;dx<3;dx++){
            int xx = p2+dx-1;
            if (xx>=0 && xx<8) acc = fmaf(wp[dy*3+dx], bufA[ch*64 + yy*8+xx], acc);
          }
        }
      }
      cvals[kk]=acc; s+=acc; s2+=acc*acc;
    }
    block_reduce2<8>(s,s2,red);
    mean = s*(1.f/4096.f);
    rstd = rsqrtf(s2*(1.f/4096.f) - mean*mean + 1e-5f);
    #pragma unroll
    for (int kk=0;kk<8;kk++){
      int idx = kk*512+t;
      int ch = idx>>6, sp = idx&63;
      int c = g*64+ch;
      float f = (cvals[kk]-mean)*rstd*cnw[c] + cnb[c];
      float v = bufA[idx] + gelu_exact(f);
      *(short*)(smem + sp*YNT_PITCH + (size_t)c*2) = f2b(v);
    }
    __syncthreads();  // bufA reused next group / phase 2
  }

  // zero vT pad cols e=48..63 (valid-col stores never touch them)
  for (int idx = t; idx < 2*64*16; idx += 512){
    int hl = idx >> 10, rem = idx & 1023;
    int n = rem >> 4, e = 48 + (rem & 15);
    *(short*)(smem + VO + hl*9216 + n*144 + e*2) = 0;
  }

  // ---- Phase 2: MFMA attention, 2 heads per chunk ----
  const int wv = t >> 6;
  const int ln = t & 63;
  const int kbase = (ln >> 4) * 8;
  const int l15 = ln & 15;

  for (int cc = 0; cc < 8; ++cc){
    const int h0 = cc*2;
    // QKV: 36 (mat,group) GEMMs, M=8 (2 heads x 4 rows), K=64, N=64
    for (int p = wv; p < 36; p += 8){
      int mat = p < 12 ? 0 : (p < 24 ? 1 : 2);
      int g = p - mat*12;
      const float* W; const float* bias;
      if (mat==0){ W=qw; bias=qb; } else if (mat==1){ W=kw; bias=kb; } else { W=vw; bias=vb; }
      int j = ln & 7;
      int cr = (4*g + (j & 3))*16 + h0 + (j >> 2);
      short8 aF[2];
      #pragma unroll
      for (int ks=0; ks<2; ++ks){
        const float* wp = W + cr*64 + ks*32 + kbase;
        float4 w0 = *(const float4*)(wp);
        float4 w1 = *(const float4*)(wp+4);
        short8 a;
        a[0]=f2b(w0.x); a[1]=f2b(w0.y); a[2]=f2b(w0.z); a[3]=f2b(w0.w);
        a[4]=f2b(w1.x); a[5]=f2b(w1.y); a[6]=f2b(w1.z); a[7]=f2b(w1.w);
        aF[ks]=a;
      }
      #pragma unroll
      for (int nt=0; nt<4; ++nt){
        f32x4 acc = {0.f,0.f,0.f,0.f};
        #pragma unroll
        for (int ks=0; ks<2; ++ks){
          short8 bfr = *(const short8*)(smem + (16*nt + l15)*YNT_PITCH + (g*64 + ks*32 + kbase)*2);
          acc = __builtin_amdgcn_mfma_f32_16x16x32_bf16(aF[ks], bfr, acc, 0, 0, 0);
        }
        int mrow = (ln >> 4)*4;
        if (mrow < 8){
          #pragma unroll
          for (int r=0;r<4;r++){
            int m = mrow + r;
            int hl = m >> 2, rr = m & 3;
            int d = 4*g + rr;
            int cch = d*16 + h0 + hl;
            int n = 16*nt + l15;
            float v = acc[r] + bias[cch];
            if (mat==0)      *(short*)(smem + QO + hl*6912 + d*144 + n*2) = f2b(v * 0.14433756729740643f);
            else if (mat==1) *(short*)(smem + KO + hl*6912 + d*144 + n*2) = f2b(v);
            else             *(short*)(smem + VO + hl*9216 + n*144 + d*2) = f2b(v);
          }
        }
      }
    }
    __syncthreads();

    for (int hl = 0; hl < 2; ++hl){
      const int h = h0 + hl;
      // S = q k^T : triangular tiles (dt,et<=dt), 6 units on waves 0..5
      if (wv < 6){
        int dt = (wv==0) ? 0 : (wv<3 ? 1 : 2);
        int et = (wv==0) ? 0 : (wv<3 ? wv-1 : wv-3);
        f32x4 acc = {0.f,0.f,0.f,0.f};
        #pragma unroll
        for (int ks=0; ks<2; ++ks){
          short8 a = *(const short8*)(smem + QO + hl*6912 + (16*dt + l15)*144 + (ks*32 + kbase)*2);
          short8 bfr = *(const short8*)(smem + KO + hl*6912 + (16*et + l15)*144 + (ks*32 + kbase)*2);
          acc = __builtin_amdgcn_mfma_f32_16x16x32_bf16(a, bfr, acc, 0, 0, 0);
        }
        #pragma unroll
        for (int r=0;r<4;++r){
          int d = 16*dt + (ln>>4)*4 + r;
          int e = 16*et + l15;
          *(float*)(smem + SO + d*208 + e*4) = acc[r];
        }
      }
      __syncthreads();
      // masked softmax (block-causal: e <= d|3), 4 lanes per row
      if (t < 192){
        int d = t >> 2, lid = t & 3;
        float* Sr = (float*)(smem + SO + d*208);
        int emax = d | 3;
        float mx = -1e30f;
        for (int e = lid; e <= emax; e += 4) mx = fmaxf(mx, Sr[e]);
        mx = fmaxf(mx, __shfl_xor(mx, 1));
        mx = fmaxf(mx, __shfl_xor(mx, 2));
        float sm = 0.f;
        for (int e = lid; e <= emax; e += 4){ float p = expf(Sr[e]-mx); Sr[e]=p; sm += p; }
        sm += __shfl_xor(sm, 1);
        sm += __shfl_xor(sm, 2);
        float inv = 1.f / sm;
        short* Pr = (short*)(smem + PO + d*144);
        for (int e = lid; e < 64; e += 4){
          float pv = (e <= emax) ? Sr[e]*inv : 0.f;
          Pr[e] = f2b(pv);
        }
      }
      __syncthreads();
      // PV: out[d][n] = P @ V, 12 units (dt,nt); dt<2 needs 1 kstep (P zero-padded)
      for (int u = wv; u < 12; u += 8){
        int dt = u >> 2, nt = u & 3;
        int nks = (dt==2) ? 2 : 1;
        f32x4 acc = {0.f,0.f,0.f,0.f};
        for (int ks=0; ks<nks; ++ks){
          short8 a = *(const short8*)(smem + PO + (16*dt + l15)*144 + (ks*32 + kbase)*2);
          short8 bfr = *(const short8*)(smem + VO + hl*9216 + (16*nt + l15)*144 + (ks*32 + kbase)*2);
          acc = __builtin_amdgcn_mfma_f32_16x16x32_bf16(a, bfr, acc, 0, 0, 0);
        }
        #pragma unroll
        for (int r=0;r<4;++r){
          int d = 16*dt + (ln>>4)*4 + r;
          int cch = d*16 + h;
          int n = 16*nt + l15;
          out[ybase + (size_t)cch*NPOS + (n>>3)*IMG + (n&7)] = acc[r];
        }
      }
      __syncthreads();
    }
  }
}

// ---------------- K2: grouped proj + residual (in-place on d_out) + norm2 partials ----
__global__ __launch_bounds__(256) void k2_proj(
    const float* __restrict__ y,
    const float* __restrict__ pw, const float* __restrict__ pb,
    float* __restrict__ io, float* __restrict__ part)
{
  const int t = threadIdx.x;
  const int tile = blockIdx.x;   // 0..255
  const int g = blockIdx.y;      // 0..11
  const int b = blockIdx.z;      // 0..1
  const int pos = tile*256 + t;
  const size_t base = ((size_t)(b*768 + g*64))*NPOS + pos;
  float x[64];
  #pragma unroll
  for (int i=0;i<64;i++) x[i] = io[base + (size_t)i*NPOS];
  float s=0.f, s2=0.f;
  for (int cp=0; cp<64; ++cp){
    const float* wr = pw + (g*64+cp)*64;
    float a0=0,a1=0,a2=0,a3=0;
    #pragma unroll
    for (int i=0;i<64;i+=4){
      a0 = fmaf(wr[i+0], x[i+0], a0);
      a1 = fmaf(wr[i+1], x[i+1], a1);
      a2 = fmaf(wr[i+2], x[i+2], a2);
      a3 = fmaf(wr[i+3], x[i+3], a3);
    }
    float o = y[base + (size_t)cp*NPOS] + pb[g*64+cp] + ((a0+a1)+(a2+a3));
    io[base + (size_t)cp*NPOS] = o;
    s += o; s2 += o*o;
  }
  __shared__ float red[10];
  block_reduce2<4>(s,s2,red);
  if (t==0){
    int bg = b*12+g;
    part[(size_t)(bg*256+tile)*2+0] = s;
    part[(size_t)(bg*256+tile)*2+1] = s2;
  }
}

// ---------------- K3: finalize norm2 stats (deterministic) ----------------
__global__ __launch_bounds__(256) void k3_stats(
    const float* __restrict__ part, float* __restrict__ stats)
{
  const int bg = blockIdx.x;  // 0..23
  const int t = threadIdx.x;
  float s  = part[(size_t)(bg*256+t)*2+0];
  float s2 = part[(size_t)(bg*256+t)*2+1];
  __shared__ float red[10];
  block_reduce2<4>(s,s2,red);
  if (t==0){
    const float Ninv = 1.f/(64.f*65536.f);
    float mean = s*Ninv;
    float var  = s2*Ninv - mean*mean;
    stats[bg*2+0] = mean;
    stats[bg*2+1] = rsqrtf(var + 1e-5f);
  }
}

// ---------------- K4: norm2 + f1 + gelu + f2 + residual (in-place) ----------------
__global__ __launch_bounds__(256) void k4_mlp(
    const float* __restrict__ n2w, const float* __restrict__ n2b,
    const float* __restrict__ f1w, const float* __restrict__ f1b,
    const float* __restrict__ f2w, const float* __restrict__ f2b,
    const float* __restrict__ stats,
    float* __restrict__ io)
{
  __shared__ float hl[64*256];   // h staged via LDS (avoid runtime-indexed reg array)
  const int t = threadIdx.x;
  const int tile = blockIdx.x;
  const int g = blockIdx.y;
  const int b = blockIdx.z;
  const int pos = tile*256 + t;
  const int bg = b*12+g;
  const float mean = stats[bg*2+0], rstd = stats[bg*2+1];
  const size_t base = ((size_t)(b*768 + g*64))*NPOS + pos;
  float xn[64];
  #pragma unroll
  for (int i=0;i<64;i++){
    float v = io[base + (size_t)i*NPOS];
    xn[i] = (v-mean)*rstd*n2w[g*64+i] + n2b[g*64+i];
  }
  for (int cp=0; cp<64; ++cp){
    const float* wr = f1w + (g*64+cp)*64;
    float a0=0,a1=0,a2=0,a3=0;
    #pragma unroll
    for (int i=0;i<64;i+=4){
      a0 = fmaf(wr[i+0], xn[i+0], a0);
      a1 = fmaf(wr[i+1], xn[i+1], a1);
      a2 = fmaf(wr[i+2], xn[i+2], a2);
      a3 = fmaf(wr[i+3], xn[i+3], a3);
    }
    hl[cp*256+t] = gelu_exact(f1b[g*64+cp] + ((a0+a1)+(a2+a3)));
  }
  float hr[64];
  #pragma unroll
  for (int i=0;i<64;i++) hr[i] = hl[i*256+t];
  for (int cp=0; cp<64; ++cp){
    const float* wr = f2w + (g*64+cp)*64;
    float a0=0,a1=0,a2=0,a3=0;
    #pragma unroll
    for (int i=0;i<64;i+=4){
      a0 = fmaf(wr[i+0], hr[i+0], a0);
      a1 = fmaf(wr[i+1], hr[i+1], a1);
      a2 = fmaf(wr[i+2], hr[i+2], a2);
      a3 = fmaf(wr[i+3], hr[i+3], a3);
    }
    float o = io[base + (size_t)cp*NPOS] + f2b[g*64+cp] + ((a0+a1)+(a2+a3));
    io[base + (size_t)cp*NPOS] = o;
  }
}

extern "C" void kernel_launch(void* const* d_in, const int* in_sizes, int n_in,
                              void* d_out, int out_size, void* d_ws, size_t ws_size,
                              hipStream_t stream){
  const float* y    = (const float*)d_in[0];
  const float* n1w  = (const float*)d_in[1];
  const float* n1b  = (const float*)d_in[2];
  const float* cw   = (const float*)d_in[3];
  const float* cb   = (const float*)d_in[4];
  const float* cnw  = (const float*)d_in[5];
  const float* cnb  = (const float*)d_in[6];
  const float* qw   = (const float*)d_in[7];
  const float* qb   = (const float*)d_in[8];
  const float* kw   = (const float*)d_in[9];
  const float* kb   = (const float*)d_in[10];
  const float* vw   = (const float*)d_in[11];
  const float* vb   = (const float*)d_in[12];
  const float* pw   = (const float*)d_in[13];
  const float* pb   = (const float*)d_in[14];
  const float* n2w  = (const float*)d_in[15];
  const float* n2b  = (const float*)d_in[16];
  const float* f1w  = (const float*)d_in[17];
  const float* f1b  = (const float*)d_in[18];
  const float* f2w  = (const float*)d_in[19];
  const float* f2b  = (const float*)d_in[20];
  float* out   = (float*)d_out;
  float* part  = (float*)d_ws;                 // 24*256*2 f32 = 48 KB
  float* stats = part + 24*256*2;              // 48 f32

  hipLaunchKernelGGL(k1_attn, dim3(2048), dim3(512), LDS_TOTAL, stream,
                     y, n1w,n1b, cw,cb, cnw,cnb, qw,qb, kw,kb, vw,vb, out);
  hipLaunchKernelGGL(k2_proj, dim3(256,12,2), dim3(256), 0, stream, y, pw, pb, out, part);
  hipLaunchKernelGGL(k3_stats, dim3(24), dim3(256), 0, stream, part, stats);
  hipLaunchKernelGGL(k4_mlp, dim3(256,12,2), dim3(256), 0, stream,
                     n2w,n2b, f1w,f1b, f2w,f2b, stats, out);
}

// Round 3
// 2980.557 us; speedup vs baseline: 2.1275x; 1.3554x over previous
//
#include <hip/hip_runtime.h>
#include <hip/hip_bf16.h>

#define IMG 256
#define NPOS 65536

typedef __attribute__((ext_vector_type(8))) short short8;
typedef __attribute__((ext_vector_type(4))) float f32x4;

__device__ __forceinline__ float gelu_exact(float x){
  return 0.5f * x * (1.0f + erff(x * 0.7071067811865475f));
}

__device__ __forceinline__ short f2b(float x){
  __hip_bfloat16 hh = __float2bfloat16(x);
  short s;
  __builtin_memcpy(&s, &hh, sizeof(s));
  return s;
}

template<int NWAVES>
__device__ __forceinline__ void block_reduce2(float& s, float& s2, float* red){
  __syncthreads();  // protect red[] reuse from previous call
  #pragma unroll
  for (int off=32; off>0; off>>=1){ s += __shfl_down(s, off); s2 += __shfl_down(s2, off); }
  int lane = threadIdx.x & 63, w = threadIdx.x >> 6;
  if (lane==0){ red[w*2]=s; red[w*2+1]=s2; }
  __syncthreads();
  if (threadIdx.x==0){
    float a=0.f, bb=0.f;
    #pragma unroll
    for (int i=0;i<NWAVES;i++){ a+=red[i*2]; bb+=red[i*2+1]; }
    red[2*NWAVES]=a; red[2*NWAVES+1]=bb;
  }
  __syncthreads();
  s=red[2*NWAVES]; s2=red[2*NWAVES+1];
}

// ---------------- K_A: norm1 + CPE -> ynT bf16 [pos_local][768] ----------------
// grid = NW windows, 512 threads, LDS ~17 KB
__global__ __launch_bounds__(512) void k_a(
    const float* __restrict__ y,
    const float* __restrict__ n1w, const float* __restrict__ n1b,
    const float* __restrict__ cw,  const float* __restrict__ cb,
    const float* __restrict__ cnw, const float* __restrict__ cnb,
    short* __restrict__ ynT, int win0)
{
  __shared__ float bufA[64*65];   // +1 pad: bank = (ch + sp) mod 32
  __shared__ float red[18];
  const int t = threadIdx.x;
  const int win = win0 + blockIdx.x;
  const int b = win >> 10, W1 = (win>>5)&31, W2 = win&31;
  const size_t ybase = (size_t)b*768*(size_t)NPOS + (size_t)(W1*8)*IMG + (W2*8);
  const int posb = blockIdx.x * 64;

  for (int g=0; g<12; ++g){
    // mapping A: thread t -> ch = t>>3, sp = (t&7)*8 + kk (vectorized row loads)
    const int ch = t>>3, r8 = t&7;
    const float* yp = y + ybase + (size_t)(g*64+ch)*NPOS + (size_t)r8*IMG;
    float4 v0 = *(const float4*)yp;
    float4 v1 = *(const float4*)(yp+4);
    float vals[8] = {v0.x,v0.y,v0.z,v0.w,v1.x,v1.y,v1.z,v1.w};
    float s=0.f, s2=0.f;
    #pragma unroll
    for (int kk=0;kk<8;kk++){ s+=vals[kk]; s2+=vals[kk]*vals[kk]; }
    block_reduce2<8>(s,s2,red);
    float mean = s * (1.f/4096.f);
    float rstd = rsqrtf(s2*(1.f/4096.f) - mean*mean + 1e-5f);
    float nw_ = n1w[g*64+ch], nb_ = n1b[g*64+ch];
    #pragma unroll
    for (int kk=0;kk<8;kk++)
      bufA[ch*65 + r8*8 + kk] = (vals[kk]-mean)*rstd*nw_ + nb_;
    __syncthreads();

    // mapping B: thread t -> sp = t&63, ch2 = (t>>6)*8 + kk2 (contiguous ch for 16B store)
    const int sp = t&63, p1 = sp>>3, p2 = sp&7;
    float cv[8];
    s=0.f; s2=0.f;
    #pragma unroll
    for (int kk2=0;kk2<8;kk2++){
      int ch2 = (t>>6)*8 + kk2;
      int c2 = g*64 + ch2;
      const float* wp = cw + c2*9;
      float acc = cb[c2];
      #pragma unroll
      for (int dy=0;dy<3;dy++){
        int yy = p1+dy-1;
        if (yy>=0 && yy<8){
          #pragma unroll
          for (int dx=0;dx<3;dx++){
            int xx = p2+dx-1;
            if (xx>=0 && xx<8) acc = fmaf(wp[dy*3+dx], bufA[ch2*65 + yy*8+xx], acc);
          }
        }
      }
      cv[kk2]=acc; s+=acc; s2+=acc*acc;
    }
    block_reduce2<8>(s,s2,red);
    float mean2 = s*(1.f/4096.f);
    float rstd2 = rsqrtf(s2*(1.f/4096.f) - mean2*mean2 + 1e-5f);
    short8 pk;
    #pragma unroll
    for (int kk2=0;kk2<8;kk2++){
      int ch2 = (t>>6)*8 + kk2;
      int c2 = g*64 + ch2;
      float f = (cv[kk2]-mean2)*rstd2*cnw[c2] + cnb[c2];
      float val = bufA[ch2*65+sp] + gelu_exact(f);
      pk[kk2] = f2b(val);
    }
    *(short8*)&ynT[(size_t)(posb+sp)*768 + g*64 + (t>>6)*8] = pk;
    __syncthreads();
  }
}

// ---------------- K_B: qkv grouped GEMM (MFMA), no LDS ----------------
// grid (12, NW/8): block = (group g, 512 positions), 256 threads
__global__ __launch_bounds__(256) void k_b(
    const short* __restrict__ ynT,
    const float* __restrict__ qw, const float* __restrict__ qb,
    const float* __restrict__ kw, const float* __restrict__ kb,
    const float* __restrict__ vw, const float* __restrict__ vb,
    short* __restrict__ qG, short* __restrict__ kG, short* __restrict__ vG)
{
  const int g = blockIdx.x, nb = blockIdx.y;
  const int t = threadIdx.x, wv = t>>6, ln = t&63;
  const int l15 = ln&15, kb8 = (ln>>4)*8;

  short8 afr[12][2];
  float bias[12][4];
  #pragma unroll
  for (int mt=0; mt<12; ++mt){
    const float* W  = (mt<4)? qw : ((mt<8)? kw : vw);
    const float* Bb = (mt<4)? qb : ((mt<8)? kb : vb);
    const int mt2 = mt&3;
    const int row = g*64 + mt2*16 + l15;
    #pragma unroll
    for (int ks=0;ks<2;++ks){
      const float* wp = W + row*64 + ks*32 + kb8;
      float4 w0 = *(const float4*)wp;
      float4 w1 = *(const float4*)(wp+4);
      short8 a;
      a[0]=f2b(w0.x); a[1]=f2b(w0.y); a[2]=f2b(w0.z); a[3]=f2b(w0.w);
      a[4]=f2b(w1.x); a[5]=f2b(w1.y); a[6]=f2b(w1.z); a[7]=f2b(w1.w);
      afr[mt][ks]=a;
    }
    #pragma unroll
    for (int r=0;r<4;++r)
      bias[mt][r] = Bb[g*64 + mt2*16 + (ln>>4)*4 + r];
  }

  for (int tile = wv; tile < 32; tile += 4){
    const int pos0 = nb*512 + tile*16;
    const short* bp = ynT + (size_t)(pos0 + l15)*768 + g*64 + kb8;
    short8 b0 = *(const short8*)(bp);
    short8 b1 = *(const short8*)(bp + 32);
    const int pos = pos0 + l15;
    const int wl = pos>>6, nwin = pos&63;
    #pragma unroll
    for (int mt=0; mt<12; ++mt){
      f32x4 acc = {0.f,0.f,0.f,0.f};
      acc = __builtin_amdgcn_mfma_f32_16x16x32_bf16(afr[mt][0], b0, acc, 0,0,0);
      acc = __builtin_amdgcn_mfma_f32_16x16x32_bf16(afr[mt][1], b1, acc, 0,0,0);
      const int mt2 = mt&3;
      #pragma unroll
      for (int r=0;r<4;++r){
        const int hh = (ln>>4)*4 + r;        // head = ci & 15
        float val = acc[r] + bias[mt][r];
        size_t addr = ((size_t)(wl*16 + hh)*48 + 4*g + mt2)*64 + nwin;
        if (mt<4)      qG[addr] = f2b(val * 0.14433756729740643f);
        else if (mt<8) kG[addr] = f2b(val);
        else           vG[addr] = f2b(val);
      }
    }
  }
}

// ---------------- K_C: per (window, head) attention, 1 wave, no barriers ----------------
__global__ __launch_bounds__(64) void k_c(
    const short* __restrict__ qG, const short* __restrict__ kG,
    const short* __restrict__ vG, float* __restrict__ out, int win0)
{
  __shared__ short lds_vT[64*64];   // [n][e] XOR-swizzled, e 48..63 zero
  __shared__ short lds_P[48*64];    // [d][e] XOR-swizzled, zero-initialized
  const int ln = threadIdx.x;
  const int wl = blockIdx.x >> 4, h = blockIdx.x & 15;
  const int win = win0 + wl;
  const int b = win >> 10, W1 = (win>>5)&31, W2 = win&31;
  const size_t ybase = (size_t)b*768*(size_t)NPOS + (size_t)(W1*8)*IMG + (W2*8);
  const int l15 = ln & 15, kb8 = (ln>>4)*8, rbase = (ln>>4)*4;
  const size_t hbase = (size_t)(wl*16 + h)*48;

  // zero P (covers masked tiles and e>=48 pad)
  short8 z8 = {0,0,0,0,0,0,0,0};
  #pragma unroll
  for (int k_=0;k_<6;++k_) ((short8*)lds_P)[k_*64 + ln] = z8;

  // stage vT: lane = e row (>=48 -> zeros); swizzle byte = n*128 + (((e>>3)^(n&7))<<4) + (e&7)*2
  #pragma unroll
  for (int nblk=0;nblk<8;++nblk){
    short8 v8 = z8;
    if (ln < 48) v8 = *(const short8*)&vG[(hbase + ln)*64 + nblk*8];
    #pragma unroll
    for (int j=0;j<8;++j){
      int n = nblk*8 + j;
      lds_vT[n*64 + (((ln>>3) ^ (n&7))<<3) + (ln&7)] = v8[j];
    }
  }

  // K/Q fragments (A = K rows -> computes S^T so softmax is lane-local per column d)
  short8 kf[3][2], qf[3][2];
  #pragma unroll
  for (int tt=0;tt<3;++tt)
    #pragma unroll
    for (int ks=0;ks<2;++ks){
      kf[tt][ks] = *(const short8*)&kG[(hbase + 16*tt + l15)*64 + ks*32 + kb8];
      qf[tt][ks] = *(const short8*)&qG[(hbase + 16*tt + l15)*64 + ks*32 + kb8];
    }

  // S^T tiles: D[e][d], triangular (et <= dt)
  f32x4 Su[6];
  const int DTa[6] = {0,1,1,2,2,2};
  const int ETa[6] = {0,0,1,0,1,2};
  #pragma unroll
  for (int u=0;u<6;++u){
    f32x4 acc = {0.f,0.f,0.f,0.f};
    acc = __builtin_amdgcn_mfma_f32_16x16x32_bf16(kf[ETa[u]][0], qf[DTa[u]][0], acc, 0,0,0);
    acc = __builtin_amdgcn_mfma_f32_16x16x32_bf16(kf[ETa[u]][1], qf[DTa[u]][1], acc, 0,0,0);
    Su[u] = acc;
  }

  // in-register masked softmax per dt; d = 16dt + l15, e = 16et + rbase + r
  #pragma unroll
  for (int dt=0;dt<3;++dt){
    const int ub = (dt==0)?0:((dt==1)?1:3);
    float m = -1e30f;
    #pragma unroll
    for (int et=0; et<=dt; ++et)
      #pragma unroll
      for (int r=0;r<4;++r){
        bool valid = (et<dt) || ((rbase + r) <= (l15|3));
        if (valid) m = fmaxf(m, Su[ub+et][r]);
      }
    m = fmaxf(m, __shfl_xor(m,16));
    m = fmaxf(m, __shfl_xor(m,32));
    float pv[3][4];
    float sm = 0.f;
    #pragma unroll
    for (int et=0; et<=dt; ++et)
      #pragma unroll
      for (int r=0;r<4;++r){
        bool valid = (et<dt) || ((rbase + r) <= (l15|3));
        float p = valid ? expf(Su[ub+et][r] - m) : 0.f;
        pv[et][r] = p; sm += p;
      }
    sm += __shfl_xor(sm,16);
    sm += __shfl_xor(sm,32);
    float inv = 1.f/sm;
    const int d = 16*dt + l15;
    #pragma unroll
    for (int et=0; et<=dt; ++et)
      #pragma unroll
      for (int r=0;r<4;++r){
        int e = 16*et + rbase + r;
        lds_P[d*64 + (((e>>3) ^ (d&7))<<3) + (e&7)] = f2b(pv[et][r]*inv);
      }
  }

  // PV: out[d][n] = P @ V ; a-frags (dt,ks) in {(0,0),(1,0),(2,0),(2,1)}
  short8 aP[4];
  const int PDT[4] = {0,1,2,2}, PKS[4] = {0,0,0,1};
  #pragma unroll
  for (int i_=0;i_<4;++i_){
    int d = 16*PDT[i_] + l15;
    int ch = PKS[i_]*4 + (ln>>4);
    aP[i_] = *(const short8*)&lds_P[d*64 + ((ch ^ (d&7))<<3)];
  }
  #pragma unroll
  for (int nt=0;nt<4;++nt){
    const int n = 16*nt + l15;
    const int ch0 = (ln>>4);
    short8 bv0 = *(const short8*)&lds_vT[n*64 + ((ch0 ^ (n&7))<<3)];
    short8 bv1 = *(const short8*)&lds_vT[n*64 + (((4+ch0) ^ (n&7))<<3)];
    f32x4 O0 = {0.f,0.f,0.f,0.f};
    f32x4 O1 = {0.f,0.f,0.f,0.f};
    f32x4 O2 = {0.f,0.f,0.f,0.f};
    O0 = __builtin_amdgcn_mfma_f32_16x16x32_bf16(aP[0], bv0, O0, 0,0,0);
    O1 = __builtin_amdgcn_mfma_f32_16x16x32_bf16(aP[1], bv0, O1, 0,0,0);
    O2 = __builtin_amdgcn_mfma_f32_16x16x32_bf16(aP[2], bv0, O2, 0,0,0);
    O2 = __builtin_amdgcn_mfma_f32_16x16x32_bf16(aP[3], bv1, O2, 0,0,0);
    const size_t obase = ybase + ((size_t)(n>>3))*IMG + (n&7);
    #pragma unroll
    for (int r=0;r<4;++r){
      int d0 = rbase + r;
      out[obase + (size_t)((d0      )*16 + h)*NPOS] = O0[r];
      out[obase + (size_t)((d0 + 16 )*16 + h)*NPOS] = O1[r];
      out[obase + (size_t)((d0 + 32 )*16 + h)*NPOS] = O2[r];
    }
  }
}

// ---------------- K2: grouped proj + residual (in-place on d_out) + norm2 partials ----
__global__ __launch_bounds__(256) void k2_proj(
    const float* __restrict__ y,
    const float* __restrict__ pw, const float* __restrict__ pb,
    float* __restrict__ io, float* __restrict__ part)
{
  const int t = threadIdx.x;
  const int tile = blockIdx.x;   // 0..255
  const int g = blockIdx.y;      // 0..11
  const int b = blockIdx.z;      // 0..1
  const int pos = tile*256 + t;
  const size_t base = ((size_t)(b*768 + g*64))*NPOS + pos;
  float x[64];
  #pragma unroll
  for (int i=0;i<64;i++) x[i] = io[base + (size_t)i*NPOS];
  float s=0.f, s2=0.f;
  for (int cp=0; cp<64; ++cp){
    const float* wr = pw + (g*64+cp)*64;
    float a0=0,a1=0,a2=0,a3=0;
    #pragma unroll
    for (int i=0;i<64;i+=4){
      a0 = fmaf(wr[i+0], x[i+0], a0);
      a1 = fmaf(wr[i+1], x[i+1], a1);
      a2 = fmaf(wr[i+2], x[i+2], a2);
      a3 = fmaf(wr[i+3], x[i+3], a3);
    }
    float o = y[base + (size_t)cp*NPOS] + pb[g*64+cp] + ((a0+a1)+(a2+a3));
    io[base + (size_t)cp*NPOS] = o;
    s += o; s2 += o*o;
  }
  __shared__ float red[10];
  block_reduce2<4>(s,s2,red);
  if (t==0){
    int bg = b*12+g;
    part[(size_t)(bg*256+tile)*2+0] = s;
    part[(size_t)(bg*256+tile)*2+1] = s2;
  }
}

// ---------------- K3: finalize norm2 stats (deterministic) ----------------
__global__ __launch_bounds__(256) void k3_stats(
    const float* __restrict__ part, float* __restrict__ stats)
{
  const int bg = blockIdx.x;  // 0..23
  const int t = threadIdx.x;
  float s  = part[(size_t)(bg*256+t)*2+0];
  float s2 = part[(size_t)(bg*256+t)*2+1];
  __shared__ float red[10];
  block_reduce2<4>(s,s2,red);
  if (t==0){
    const float Ninv = 1.f/(64.f*65536.f);
    float mean = s*Ninv;
    float var  = s2*Ninv - mean*mean;
    stats[bg*2+0] = mean;
    stats[bg*2+1] = rsqrtf(var + 1e-5f);
  }
}

// ---------------- K4: norm2 + f1 + gelu + f2 + residual (in-place) ----------------
__global__ __launch_bounds__(256) void k4_mlp(
    const float* __restrict__ n2w, const float* __restrict__ n2b,
    const float* __restrict__ f1w, const float* __restrict__ f1b,
    const float* __restrict__ f2w, const float* __restrict__ f2b,
    const float* __restrict__ stats,
    float* __restrict__ io)
{
  __shared__ float hl[64*256];   // h staged via LDS (avoid runtime-indexed reg array)
  const int t = threadIdx.x;
  const int tile = blockIdx.x;
  const int g = blockIdx.y;
  const int b = blockIdx.z;
  const int pos = tile*256 + t;
  const int bg = b*12+g;
  const float mean = stats[bg*2+0], rstd = stats[bg*2+1];
  const size_t base = ((size_t)(b*768 + g*64))*NPOS + pos;
  float xn[64];
  #pragma unroll
  for (int i=0;i<64;i++){
    float v = io[base + (size_t)i*NPOS];
    xn[i] = (v-mean)*rstd*n2w[g*64+i] + n2b[g*64+i];
  }
  for (int cp=0; cp<64; ++cp){
    const float* wr = f1w + (g*64+cp)*64;
    float a0=0,a1=0,a2=0,a3=0;
    #pragma unroll
    for (int i=0;i<64;i+=4){
      a0 = fmaf(wr[i+0], xn[i+0], a0);
      a1 = fmaf(wr[i+1], xn[i+1], a1);
      a2 = fmaf(wr[i+2], xn[i+2], a2);
      a3 = fmaf(wr[i+3], xn[i+3], a3);
    }
    hl[cp*256+t] = gelu_exact(f1b[g*64+cp] + ((a0+a1)+(a2+a3)));
  }
  float hr[64];
  #pragma unroll
  for (int i=0;i<64;i++) hr[i] = hl[i*256+t];
  for (int cp=0; cp<64; ++cp){
    const float* wr = f2w + (g*64+cp)*64;
    float a0=0,a1=0,a2=0,a3=0;
    #pragma unroll
    for (int i=0;i<64;i+=4){
      a0 = fmaf(wr[i+0], hr[i+0], a0);
      a1 = fmaf(wr[i+1], hr[i+1], a1);
      a2 = fmaf(wr[i+2], hr[i+2], a2);
      a3 = fmaf(wr[i+3], hr[i+3], a3);
    }
    float o = io[base + (size_t)cp*NPOS] + f2b[g*64+cp] + ((a0+a1)+(a2+a3));
    io[base + (size_t)cp*NPOS] = o;
  }
}

extern "C" void kernel_launch(void* const* d_in, const int* in_sizes, int n_in,
                              void* d_out, int out_size, void* d_ws, size_t ws_size,
                              hipStream_t stream){
  const float* y    = (const float*)d_in[0];
  const float* n1w  = (const float*)d_in[1];
  const float* n1b  = (const float*)d_in[2];
  const float* cw   = (const float*)d_in[3];
  const float* cb   = (const float*)d_in[4];
  const float* cnw  = (const float*)d_in[5];
  const float* cnb  = (const float*)d_in[6];
  const float* qw   = (const float*)d_in[7];
  const float* qb   = (const float*)d_in[8];
  const float* kw   = (const float*)d_in[9];
  const float* kb   = (const float*)d_in[10];
  const float* vw   = (const float*)d_in[11];
  const float* vb   = (const float*)d_in[12];
  const float* pw   = (const float*)d_in[13];
  const float* pb   = (const float*)d_in[14];
  const float* n2w  = (const float*)d_in[15];
  const float* n2b  = (const float*)d_in[16];
  const float* f1w  = (const float*)d_in[17];
  const float* f1b  = (const float*)d_in[18];
  const float* f2w  = (const float*)d_in[19];
  const float* f2b  = (const float*)d_in[20];
  float* out   = (float*)d_out;

  unsigned char* wsb = (unsigned char*)d_ws;
  float* part  = (float*)wsb;                 // 24*256*2 f32 = 48 KB
  float* stats = part + 24*256*2;             // 48 f32

  // adaptive chunking: pick fewest chunks whose scratch fits ws
  int C = 32;
  {
    const int cand[6] = {1,2,4,8,16,32};
    for (int i=0;i<6;++i){
      int nw = 2048 / cand[i];
      size_t Y = (size_t)nw * 64 * 768 * 2;
      if ((size_t)(1<<20) + 4*Y <= ws_size){ C = cand[i]; break; }
    }
  }
  const int nw = 2048 / C;
  const size_t Y = (size_t)nw * 64 * 768 * 2;
  short* ynT = (short*)(wsb + (1<<20));
  short* qG  = (short*)(wsb + (1<<20) + Y);
  short* kG  = (short*)(wsb + (1<<20) + 2*Y);
  short* vG  = (short*)(wsb + (1<<20) + 3*Y);

  for (int c=0; c<C; ++c){
    int win0 = c * nw;
    hipLaunchKernelGGL(k_a, dim3(nw), dim3(512), 0, stream,
                       y, n1w,n1b, cw,cb, cnw,cnb, ynT, win0);
    hipLaunchKernelGGL(k_b, dim3(12, nw/8), dim3(256), 0, stream,
                       ynT, qw,qb, kw,kb, vw,vb, qG, kG, vG);
    hipLaunchKernelGGL(k_c, dim3(nw*16), dim3(64), 0, stream,
                       qG, kG, vG, out, win0);
  }
  hipLaunchKernelGGL(k2_proj, dim3(256,12,2), dim3(256), 0, stream, y, pw, pb, out, part);
  hipLaunchKernelGGL(k3_stats, dim3(24), dim3(256), 0, stream, part, stats);
  hipLaunchKernelGGL(k4_mlp, dim3(256,12,2), dim3(256), 0, stream,
                     n2w,n2b, f1w,f1b, f2w,f2b, stats, out);
}

// Round 4
// 2723.283 us; speedup vs baseline: 2.3285x; 1.0945x over previous
//
#include <hip/hip_runtime.h>
#include <hip/hip_bf16.h>

#define IMG 256
#define NPOS 65536

typedef __attribute__((ext_vector_type(8))) short short8;
typedef __attribute__((ext_vector_type(4))) float f32x4;

__device__ __forceinline__ float gelu_exact(float x){
  return 0.5f * x * (1.0f + erff(x * 0.7071067811865475f));
}

__device__ __forceinline__ short f2b(float x){
  __hip_bfloat16 hh = __float2bfloat16(x);
  short s;
  __builtin_memcpy(&s, &hh, sizeof(s));
  return s;
}

template<int NWAVES>
__device__ __forceinline__ void block_reduce2(float& s, float& s2, float* red){
  __syncthreads();  // protect red[] reuse from previous call
  #pragma unroll
  for (int off=32; off>0; off>>=1){ s += __shfl_down(s, off); s2 += __shfl_down(s2, off); }
  int lane = threadIdx.x & 63, w = threadIdx.x >> 6;
  if (lane==0){ red[w*2]=s; red[w*2+1]=s2; }
  __syncthreads();
  if (threadIdx.x==0){
    float a=0.f, bb=0.f;
    #pragma unroll
    for (int i=0;i<NWAVES;i++){ a+=red[i*2]; bb+=red[i*2+1]; }
    red[2*NWAVES]=a; red[2*NWAVES+1]=bb;
  }
  __syncthreads();
  s=red[2*NWAVES]; s2=red[2*NWAVES+1];
}

// ---------------- K_A: norm1 + CPE -> ynT bf16 [pos_local][768] ----------------
__global__ __launch_bounds__(512) void k_a(
    const float* __restrict__ y,
    const float* __restrict__ n1w, const float* __restrict__ n1b,
    const float* __restrict__ cw,  const float* __restrict__ cb,
    const float* __restrict__ cnw, const float* __restrict__ cnb,
    short* __restrict__ ynT, int win0)
{
  __shared__ float bufA[64*65];   // +1 pad
  __shared__ float red[18];
  const int t = threadIdx.x;
  const int win = win0 + blockIdx.x;
  const int b = win >> 10, W1 = (win>>5)&31, W2 = win&31;
  const size_t ybase = (size_t)b*768*(size_t)NPOS + (size_t)(W1*8)*IMG + (W2*8);
  const int posb = blockIdx.x * 64;

  for (int g=0; g<12; ++g){
    const int ch = t>>3, r8 = t&7;
    const float* yp = y + ybase + (size_t)(g*64+ch)*NPOS + (size_t)r8*IMG;
    float4 v0 = *(const float4*)yp;
    float4 v1 = *(const float4*)(yp+4);
    float vals[8] = {v0.x,v0.y,v0.z,v0.w,v1.x,v1.y,v1.z,v1.w};
    float s=0.f, s2=0.f;
    #pragma unroll
    for (int kk=0;kk<8;kk++){ s+=vals[kk]; s2+=vals[kk]*vals[kk]; }
    block_reduce2<8>(s,s2,red);
    float mean = s * (1.f/4096.f);
    float rstd = rsqrtf(s2*(1.f/4096.f) - mean*mean + 1e-5f);
    float nw_ = n1w[g*64+ch], nb_ = n1b[g*64+ch];
    #pragma unroll
    for (int kk=0;kk<8;kk++)
      bufA[ch*65 + r8*8 + kk] = (vals[kk]-mean)*rstd*nw_ + nb_;
    __syncthreads();

    const int sp = t&63, p1 = sp>>3, p2 = sp&7;
    float cv[8];
    s=0.f; s2=0.f;
    #pragma unroll
    for (int kk2=0;kk2<8;kk2++){
      int ch2 = (t>>6)*8 + kk2;
      int c2 = g*64 + ch2;
      const float* wp = cw + c2*9;
      float acc = cb[c2];
      #pragma unroll
      for (int dy=0;dy<3;dy++){
        int yy = p1+dy-1;
        if (yy>=0 && yy<8){
          #pragma unroll
          for (int dx=0;dx<3;dx++){
            int xx = p2+dx-1;
            if (xx>=0 && xx<8) acc = fmaf(wp[dy*3+dx], bufA[ch2*65 + yy*8+xx], acc);
          }
        }
      }
      cv[kk2]=acc; s+=acc; s2+=acc*acc;
    }
    block_reduce2<8>(s,s2,red);
    float mean2 = s*(1.f/4096.f);
    float rstd2 = rsqrtf(s2*(1.f/4096.f) - mean2*mean2 + 1e-5f);
    short8 pk;
    #pragma unroll
    for (int kk2=0;kk2<8;kk2++){
      int ch2 = (t>>6)*8 + kk2;
      int c2 = g*64 + ch2;
      float f = (cv[kk2]-mean2)*rstd2*cnw[c2] + cnb[c2];
      float val = bufA[ch2*65+sp] + gelu_exact(f);
      pk[kk2] = f2b(val);
    }
    *(short8*)&ynT[(size_t)(posb+sp)*768 + g*64 + (t>>6)*8] = pk;
    __syncthreads();
  }
}

// ---------------- K_B: qkv grouped GEMM (MFMA), no LDS ----------------
__global__ __launch_bounds__(256) void k_b(
    const short* __restrict__ ynT,
    const float* __restrict__ qw, const float* __restrict__ qb,
    const float* __restrict__ kw, const float* __restrict__ kb,
    const float* __restrict__ vw, const float* __restrict__ vb,
    short* __restrict__ qG, short* __restrict__ kG, short* __restrict__ vG)
{
  const int g = blockIdx.x, nb = blockIdx.y;
  const int t = threadIdx.x, wv = t>>6, ln = t&63;
  const int l15 = ln&15, kb8 = (ln>>4)*8;

  short8 afr[12][2];
  float bias[12][4];
  #pragma unroll
  for (int mt=0; mt<12; ++mt){
    const float* W  = (mt<4)? qw : ((mt<8)? kw : vw);
    const float* Bb = (mt<4)? qb : ((mt<8)? kb : vb);
    const int mt2 = mt&3;
    const int row = g*64 + mt2*16 + l15;
    #pragma unroll
    for (int ks=0;ks<2;++ks){
      const float* wp = W + row*64 + ks*32 + kb8;
      float4 w0 = *(const float4*)wp;
      float4 w1 = *(const float4*)(wp+4);
      short8 a;
      a[0]=f2b(w0.x); a[1]=f2b(w0.y); a[2]=f2b(w0.z); a[3]=f2b(w0.w);
      a[4]=f2b(w1.x); a[5]=f2b(w1.y); a[6]=f2b(w1.z); a[7]=f2b(w1.w);
      afr[mt][ks]=a;
    }
    #pragma unroll
    for (int r=0;r<4;++r)
      bias[mt][r] = Bb[g*64 + mt2*16 + (ln>>4)*4 + r];
  }

  for (int tile = wv; tile < 32; tile += 4){
    const int pos0 = nb*512 + tile*16;
    const short* bp = ynT + (size_t)(pos0 + l15)*768 + g*64 + kb8;
    short8 b0 = *(const short8*)(bp);
    short8 b1 = *(const short8*)(bp + 32);
    const int pos = pos0 + l15;
    const int wl = pos>>6, nwin = pos&63;
    #pragma unroll
    for (int mt=0; mt<12; ++mt){
      f32x4 acc = {0.f,0.f,0.f,0.f};
      acc = __builtin_amdgcn_mfma_f32_16x16x32_bf16(afr[mt][0], b0, acc, 0,0,0);
      acc = __builtin_amdgcn_mfma_f32_16x16x32_bf16(afr[mt][1], b1, acc, 0,0,0);
      const int mt2 = mt&3;
      #pragma unroll
      for (int r=0;r<4;++r){
        const int hh = (ln>>4)*4 + r;
        float val = acc[r] + bias[mt][r];
        size_t addr = ((size_t)(wl*16 + hh)*48 + 4*g + mt2)*64 + nwin;
        if (mt<4)      qG[addr] = f2b(val * 0.14433756729740643f);
        else if (mt<8) kG[addr] = f2b(val);
        else           vG[addr] = f2b(val);
      }
    }
  }
}

// ---------------- K_C: per (window, head) attention -> aO bf16 [wl][n][c] ----------------
__global__ __launch_bounds__(64) void k_c(
    const short* __restrict__ qG, const short* __restrict__ kG,
    const short* __restrict__ vG, short* __restrict__ aO)
{
  __shared__ short lds_vT[64*64];   // [n][e] XOR-swizzled, e 48..63 zero
  __shared__ short lds_P[48*64];    // [d][e] XOR-swizzled, zero-initialized
  const int ln = threadIdx.x;
  const int wl = blockIdx.x >> 4, h = blockIdx.x & 15;
  const int l15 = ln & 15, kb8 = (ln>>4)*8, rbase = (ln>>4)*4;
  const size_t hbase = (size_t)(wl*16 + h)*48;

  short8 z8 = {0,0,0,0,0,0,0,0};
  #pragma unroll
  for (int k_=0;k_<6;++k_) ((short8*)lds_P)[k_*64 + ln] = z8;

  #pragma unroll
  for (int nblk=0;nblk<8;++nblk){
    short8 v8 = z8;
    if (ln < 48) v8 = *(const short8*)&vG[(hbase + ln)*64 + nblk*8];
    #pragma unroll
    for (int j=0;j<8;++j){
      int n = nblk*8 + j;
      lds_vT[n*64 + (((ln>>3) ^ (n&7))<<3) + (ln&7)] = v8[j];
    }
  }

  short8 kf[3][2], qf[3][2];
  #pragma unroll
  for (int tt=0;tt<3;++tt)
    #pragma unroll
    for (int ks=0;ks<2;++ks){
      kf[tt][ks] = *(const short8*)&kG[(hbase + 16*tt + l15)*64 + ks*32 + kb8];
      qf[tt][ks] = *(const short8*)&qG[(hbase + 16*tt + l15)*64 + ks*32 + kb8];
    }

  f32x4 Su[6];
  const int DTa[6] = {0,1,1,2,2,2};
  const int ETa[6] = {0,0,1,0,1,2};
  #pragma unroll
  for (int u=0;u<6;++u){
    f32x4 acc = {0.f,0.f,0.f,0.f};
    acc = __builtin_amdgcn_mfma_f32_16x16x32_bf16(kf[ETa[u]][0], qf[DTa[u]][0], acc, 0,0,0);
    acc = __builtin_amdgcn_mfma_f32_16x16x32_bf16(kf[ETa[u]][1], qf[DTa[u]][1], acc, 0,0,0);
    Su[u] = acc;
  }

  #pragma unroll
  for (int dt=0;dt<3;++dt){
    const int ub = (dt==0)?0:((dt==1)?1:3);
    float m = -1e30f;
    #pragma unroll
    for (int et=0; et<=dt; ++et)
      #pragma unroll
      for (int r=0;r<4;++r){
        bool valid = (et<dt) || ((rbase + r) <= (l15|3));
        if (valid) m = fmaxf(m, Su[ub+et][r]);
      }
    m = fmaxf(m, __shfl_xor(m,16));
    m = fmaxf(m, __shfl_xor(m,32));
    float pv[3][4];
    float sm = 0.f;
    #pragma unroll
    for (int et=0; et<=dt; ++et)
      #pragma unroll
      for (int r=0;r<4;++r){
        bool valid = (et<dt) || ((rbase + r) <= (l15|3));
        float p = valid ? expf(Su[ub+et][r] - m) : 0.f;
        pv[et][r] = p; sm += p;
      }
    sm += __shfl_xor(sm,16);
    sm += __shfl_xor(sm,32);
    float inv = 1.f/sm;
    const int d = 16*dt + l15;
    #pragma unroll
    for (int et=0; et<=dt; ++et)
      #pragma unroll
      for (int r=0;r<4;++r){
        int e = 16*et + rbase + r;
        lds_P[d*64 + (((e>>3) ^ (d&7))<<3) + (e&7)] = f2b(pv[et][r]*inv);
      }
  }

  short8 aP[4];
  const int PDT[4] = {0,1,2,2}, PKS[4] = {0,0,0,1};
  #pragma unroll
  for (int i_=0;i_<4;++i_){
    int d = 16*PDT[i_] + l15;
    int ch = PKS[i_]*4 + (ln>>4);
    aP[i_] = *(const short8*)&lds_P[d*64 + ((ch ^ (d&7))<<3)];
  }
  #pragma unroll
  for (int nt=0;nt<4;++nt){
    const int n = 16*nt + l15;
    const int ch0 = (ln>>4);
    short8 bv0 = *(const short8*)&lds_vT[n*64 + ((ch0 ^ (n&7))<<3)];
    short8 bv1 = *(const short8*)&lds_vT[n*64 + (((4+ch0) ^ (n&7))<<3)];
    f32x4 O0 = {0.f,0.f,0.f,0.f};
    f32x4 O1 = {0.f,0.f,0.f,0.f};
    f32x4 O2 = {0.f,0.f,0.f,0.f};
    O0 = __builtin_amdgcn_mfma_f32_16x16x32_bf16(aP[0], bv0, O0, 0,0,0);
    O1 = __builtin_amdgcn_mfma_f32_16x16x32_bf16(aP[1], bv0, O1, 0,0,0);
    O2 = __builtin_amdgcn_mfma_f32_16x16x32_bf16(aP[2], bv0, O2, 0,0,0);
    O2 = __builtin_amdgcn_mfma_f32_16x16x32_bf16(aP[3], bv1, O2, 0,0,0);
    short* ao = aO + (size_t)wl*49152 + (size_t)n*768 + h;
    #pragma unroll
    for (int r=0;r<4;++r){
      int d0 = rbase + r;
      ao[(d0      )*16] = f2b(O0[r]);
      ao[(d0 + 16 )*16] = f2b(O1[r]);
      ao[(d0 + 32 )*16] = f2b(O2[r]);
    }
  }
}

// ---------------- K_P: proj (MFMA) + residual + norm2 partials ----------------
// grid (nw/4, 12), 256 threads: wave = one (window, group)
__global__ __launch_bounds__(256) void k_p(
    const short* __restrict__ aO, const float* __restrict__ y,
    const float* __restrict__ pw, const float* __restrict__ pb,
    float* __restrict__ out, float* __restrict__ part, int win0)
{
  const int g = blockIdx.y;
  const int wv = threadIdx.x>>6, ln = threadIdx.x&63;
  const int wl = blockIdx.x*4 + wv;
  const int win = win0 + wl;
  const int b = win>>10, W1=(win>>5)&31, W2=win&31;
  const size_t ybase = (size_t)b*768*(size_t)NPOS + (size_t)(W1*8)*IMG + (W2*8);
  const int l15 = ln&15, kb8=(ln>>4)*8, rbase=(ln>>4)*4;

  short8 af[4][2];
  float bi[4][4];
  #pragma unroll
  for (int mt=0;mt<4;++mt){
    #pragma unroll
    for (int ks=0;ks<2;++ks){
      const float* wp = pw + (size_t)(g*64 + mt*16 + l15)*64 + ks*32 + kb8;
      float4 w0 = *(const float4*)wp, w1 = *(const float4*)(wp+4);
      short8 a;
      a[0]=f2b(w0.x); a[1]=f2b(w0.y); a[2]=f2b(w0.z); a[3]=f2b(w0.w);
      a[4]=f2b(w1.x); a[5]=f2b(w1.y); a[6]=f2b(w1.z); a[7]=f2b(w1.w);
      af[mt][ks]=a;
    }
    #pragma unroll
    for (int r=0;r<4;++r) bi[mt][r] = pb[g*64 + mt*16 + rbase + r];
  }

  f32x4 acc[4][4] = {};
  const short* ab = aO + (size_t)wl*49152 + g*64;
  #pragma unroll
  for (int nt=0;nt<4;++nt){
    short8 b0 = *(const short8*)&ab[(size_t)(nt*16 + l15)*768 + kb8];
    short8 b1 = *(const short8*)&ab[(size_t)(nt*16 + l15)*768 + 32 + kb8];
    #pragma unroll
    for (int mt=0;mt<4;++mt){
      acc[mt][nt] = __builtin_amdgcn_mfma_f32_16x16x32_bf16(af[mt][0], b0, acc[mt][nt], 0,0,0);
      acc[mt][nt] = __builtin_amdgcn_mfma_f32_16x16x32_bf16(af[mt][1], b1, acc[mt][nt], 0,0,0);
    }
  }

  float s=0.f, s2=0.f;
  #pragma unroll
  for (int mt=0;mt<4;++mt)
    #pragma unroll
    for (int nt=0;nt<4;++nt){
      const int n = nt*16 + l15;
      const size_t rowoff = ybase + (size_t)((n>>3))*IMG + (n&7);
      #pragma unroll
      for (int r=0;r<4;++r){
        int m = mt*16 + rbase + r;
        size_t ad = rowoff + (size_t)(g*64+m)*NPOS;
        float o = y[ad] + bi[mt][r] + acc[mt][nt][r];
        out[ad] = o;
        s += o; s2 += o*o;
      }
    }
  #pragma unroll
  for (int off=32; off>0; off>>=1){ s += __shfl_xor(s, off); s2 += __shfl_xor(s2, off); }
  if (ln==0){
    size_t idx = (size_t)(b*12+g)*1024 + (win&1023);
    part[idx*2+0]=s; part[idx*2+1]=s2;
  }
}

// ---------------- K3: finalize norm2 stats (deterministic) ----------------
__global__ __launch_bounds__(256) void k3_stats(
    const float* __restrict__ part, float* __restrict__ stats)
{
  const int bg = blockIdx.x;  // 0..23
  const int t = threadIdx.x;
  float s=0.f, s2=0.f;
  #pragma unroll
  for (int j=0;j<4;++j){
    size_t idx = (size_t)bg*1024 + t*4 + j;
    s  += part[idx*2+0];
    s2 += part[idx*2+1];
  }
  __shared__ float red[10];
  block_reduce2<4>(s,s2,red);
  if (t==0){
    const float Ninv = 1.f/(64.f*65536.f);
    float mean = s*Ninv;
    float var  = s2*Ninv - mean*mean;
    stats[bg*2+0] = mean;
    stats[bg*2+1] = rsqrtf(var + 1e-5f);
  }
}

// ---------------- K_D: norm2 + f1 + gelu + f2 + residual (MFMA, in-place) ----------
// grid (1024, 12, 2), 256 threads, LDS 16 KB
__global__ __launch_bounds__(256) void k_d(
    const float* __restrict__ n2w, const float* __restrict__ n2b,
    const float* __restrict__ f1w, const float* __restrict__ f1b,
    const float* __restrict__ f2w, const float* __restrict__ f2bi,
    const float* __restrict__ stats, float* __restrict__ io)
{
  __shared__ short Xb[4096];
  __shared__ short Hb[4096];
  const int t = threadIdx.x;
  const int pt = blockIdx.x, g = blockIdx.y, b = blockIdx.z;
  const int bg = b*12 + g;
  const float mean = stats[bg*2+0], rstd = stats[bg*2+1];
  const size_t base = ((size_t)(b*768 + g*64))*NPOS + (size_t)pt*64;

  {
    const int pp = t>>3, posq = t&7;
    const int ch0 = pp*2;
    const float* p0 = io + base + (size_t)ch0*NPOS + posq*8;
    float4 x00 = *(const float4*)p0;
    float4 x01 = *(const float4*)(p0+4);
    const float* p1 = p0 + NPOS;
    float4 x10 = *(const float4*)p1;
    float4 x11 = *(const float4*)(p1+4);
    float A0 = rstd*n2w[g*64+ch0],   C0 = n2b[g*64+ch0]   - mean*A0;
    float A1 = rstd*n2w[g*64+ch0+1], C1 = n2b[g*64+ch0+1] - mean*A1;
    float va[8] = {x00.x,x00.y,x00.z,x00.w,x01.x,x01.y,x01.z,x01.w};
    float vb[8] = {x10.x,x10.y,x10.z,x10.w,x11.x,x11.y,x11.z,x11.w};
    #pragma unroll
    for (int j=0;j<8;++j){
      int pos = posq*8 + j;
      unsigned int u0 = (unsigned short)f2b(va[j]*A0 + C0);
      unsigned int u1 = (unsigned short)f2b(vb[j]*A1 + C1);
      *(unsigned int*)&Xb[pos*64 + (((ch0>>3) ^ (pos&7))<<3) + (ch0&7)] = u0 | (u1<<16);
    }
  }
  __syncthreads();

  const int wv = t>>6, ln = t&63;
  const int l15 = ln&15, kb8 = (ln>>4)*8, rbase = (ln>>4)*4, c4 = ln>>4;
  const int n = wv*16 + l15;

  short8 af[4][2];
  #pragma unroll
  for (int mt=0;mt<4;++mt)
    #pragma unroll
    for (int ks=0;ks<2;++ks){
      const float* wp = f1w + (size_t)(g*64 + mt*16 + l15)*64 + ks*32 + kb8;
      float4 w0 = *(const float4*)wp, w1 = *(const float4*)(wp+4);
      short8 a;
      a[0]=f2b(w0.x); a[1]=f2b(w0.y); a[2]=f2b(w0.z); a[3]=f2b(w0.w);
      a[4]=f2b(w1.x); a[5]=f2b(w1.y); a[6]=f2b(w1.z); a[7]=f2b(w1.w);
      af[mt][ks]=a;
    }
  f32x4 h[4] = {};
  #pragma unroll
  for (int ks=0;ks<2;++ks){
    short8 bfr = *(const short8*)&Xb[n*64 + (((ks*4 + c4) ^ (n&7))<<3)];
    #pragma unroll
    for (int mt=0;mt<4;++mt)
      h[mt] = __builtin_amdgcn_mfma_f32_16x16x32_bf16(af[mt][ks], bfr, h[mt], 0,0,0);
  }
  #pragma unroll
  for (int mt=0;mt<4;++mt){
    #pragma unroll
    for (int rp=0;rp<4;rp+=2){
      int m = mt*16 + rbase + rp;
      float h0 = gelu_exact(h[mt][rp]   + f1b[g*64+m]);
      float h1 = gelu_exact(h[mt][rp+1] + f1b[g*64+m+1]);
      unsigned int u0 = (unsigned short)f2b(h0);
      unsigned int u1 = (unsigned short)f2b(h1);
      *(unsigned int*)&Hb[n*64 + (((m>>3) ^ (n&7))<<3) + (m&7)] = u0 | (u1<<16);
    }
  }
  __syncthreads();

  #pragma unroll
  for (int mt=0;mt<4;++mt)
    #pragma unroll
    for (int ks=0;ks<2;++ks){
      const float* wp = f2w + (size_t)(g*64 + mt*16 + l15)*64 + ks*32 + kb8;
      float4 w0 = *(const float4*)wp, w1 = *(const float4*)(wp+4);
      short8 a;
      a[0]=f2b(w0.x); a[1]=f2b(w0.y); a[2]=f2b(w0.z); a[3]=f2b(w0.w);
      a[4]=f2b(w1.x); a[5]=f2b(w1.y); a[6]=f2b(w1.z); a[7]=f2b(w1.w);
      af[mt][ks]=a;
    }
  f32x4 o[4] = {};
  #pragma unroll
  for (int ks=0;ks<2;++ks){
    short8 bfr = *(const short8*)&Hb[n*64 + (((ks*4 + c4) ^ (n&7))<<3)];
    #pragma unroll
    for (int mt=0;mt<4;++mt)
      o[mt] = __builtin_amdgcn_mfma_f32_16x16x32_bf16(af[mt][ks], bfr, o[mt], 0,0,0);
  }
  #pragma unroll
  for (int mt=0;mt<4;++mt)
    #pragma unroll
    for (int r=0;r<4;++r){
      int m = mt*16 + rbase + r;
      float* op = io + base + (size_t)m*NPOS + n;
      *op = *op + o[mt][r] + f2bi[g*64+m];
    }
}

extern "C" void kernel_launch(void* const* d_in, const int* in_sizes, int n_in,
                              void* d_out, int out_size, void* d_ws, size_t ws_size,
                              hipStream_t stream){
  const float* y    = (const float*)d_in[0];
  const float* n1w  = (const float*)d_in[1];
  const float* n1b  = (const float*)d_in[2];
  const float* cw   = (const float*)d_in[3];
  const float* cb   = (const float*)d_in[4];
  const float* cnw  = (const float*)d_in[5];
  const float* cnb  = (const float*)d_in[6];
  const float* qw   = (const float*)d_in[7];
  const float* qb   = (const float*)d_in[8];
  const float* kw   = (const float*)d_in[9];
  const float* kb   = (const float*)d_in[10];
  const float* vw   = (const float*)d_in[11];
  const float* vb   = (const float*)d_in[12];
  const float* pw   = (const float*)d_in[13];
  const float* pb   = (const float*)d_in[14];
  const float* n2w  = (const float*)d_in[15];
  const float* n2b  = (const float*)d_in[16];
  const float* f1w  = (const float*)d_in[17];
  const float* f1b  = (const float*)d_in[18];
  const float* f2w  = (const float*)d_in[19];
  const float* f2b  = (const float*)d_in[20];
  float* out   = (float*)d_out;

  unsigned char* wsb = (unsigned char*)d_ws;
  float* part  = (float*)wsb;                 // 24*1024*2 f32 = 196 KB
  float* stats = part + 24*1024*2;            // 48 f32

  // adaptive chunking: 5 buffers (ynT, q, k, v, aO) of Y bytes each
  int C = 32;
  {
    const int cand[6] = {1,2,4,8,16,32};
    for (int i=0;i<6;++i){
      int nw = 2048 / cand[i];
      size_t Y = (size_t)nw * 64 * 768 * 2;
      if ((size_t)(1<<20) + 5*Y <= ws_size){ C = cand[i]; break; }
    }
  }
  const int nw = 2048 / C;
  const size_t Y = (size_t)nw * 64 * 768 * 2;
  short* ynT = (short*)(wsb + (1<<20));
  short* qG  = (short*)(wsb + (1<<20) + Y);
  short* kG  = (short*)(wsb + (1<<20) + 2*Y);
  short* vG  = (short*)(wsb + (1<<20) + 3*Y);
  short* aO  = (short*)(wsb + (1<<20) + 4*Y);

  for (int c=0; c<C; ++c){
    int win0 = c * nw;
    hipLaunchKernelGGL(k_a, dim3(nw), dim3(512), 0, stream,
                       y, n1w,n1b, cw,cb, cnw,cnb, ynT, win0);
    hipLaunchKernelGGL(k_b, dim3(12, nw/8), dim3(256), 0, stream,
                       ynT, qw,qb, kw,kb, vw,vb, qG, kG, vG);
    hipLaunchKernelGGL(k_c, dim3(nw*16), dim3(64), 0, stream,
                       qG, kG, vG, aO);
    hipLaunchKernelGGL(k_p, dim3(nw/4, 12), dim3(256), 0, stream,
                       aO, y, pw, pb, out, part, win0);
  }
  hipLaunchKernelGGL(k3_stats, dim3(24), dim3(256), 0, stream, part, stats);
  hipLaunchKernelGGL(k_d, dim3(1024, 12, 2), dim3(256), 0, stream,
                     n2w,n2b, f1w,f1b, f2w,f2b, stats, out);
}

// Round 5
// 2018.318 us; speedup vs baseline: 3.1418x; 1.3493x over previous
//
#include <hip/hip_runtime.h>
#include <hip/hip_bf16.h>

#define IMG 256
#define NPOS 65536

typedef __attribute__((ext_vector_type(8))) short short8;
typedef __attribute__((ext_vector_type(4))) float f32x4;

__device__ __forceinline__ float gelu_exact(float x){
  return 0.5f * x * (1.0f + erff(x * 0.7071067811865475f));
}

__device__ __forceinline__ short f2b(float x){
  __hip_bfloat16 hh = __float2bfloat16(x);
  short s;
  __builtin_memcpy(&s, &hh, sizeof(s));
  return s;
}

template<int NWAVES>
__device__ __forceinline__ void block_reduce2(float& s, float& s2, float* red){
  __syncthreads();  // protect red[] reuse from previous call
  #pragma unroll
  for (int off=32; off>0; off>>=1){ s += __shfl_down(s, off); s2 += __shfl_down(s2, off); }
  int lane = threadIdx.x & 63, w = threadIdx.x >> 6;
  if (lane==0){ red[w*2]=s; red[w*2+1]=s2; }
  __syncthreads();
  if (threadIdx.x==0){
    float a=0.f, bb=0.f;
    #pragma unroll
    for (int i=0;i<NWAVES;i++){ a+=red[i*2]; bb+=red[i*2+1]; }
    red[2*NWAVES]=a; red[2*NWAVES+1]=bb;
  }
  __syncthreads();
  s=red[2*NWAVES]; s2=red[2*NWAVES+1];
}

// ---------------- K_A: norm1 + CPE -> ynT bf16 [pos_local][768] ----------------
__global__ __launch_bounds__(512) void k_a(
    const float* __restrict__ y,
    const float* __restrict__ n1w, const float* __restrict__ n1b,
    const float* __restrict__ cw,  const float* __restrict__ cb,
    const float* __restrict__ cnw, const float* __restrict__ cnb,
    short* __restrict__ ynT, int win0)
{
  __shared__ float bufA[64*65];   // +1 pad
  __shared__ float red[18];
  const int t = threadIdx.x;
  const int win = win0 + blockIdx.x;
  const int b = win >> 10, W1 = (win>>5)&31, W2 = win&31;
  const size_t ybase = (size_t)b*768*(size_t)NPOS + (size_t)(W1*8)*IMG + (W2*8);
  const int posb = blockIdx.x * 64;

  for (int g=0; g<12; ++g){
    const int ch = t>>3, r8 = t&7;
    const float* yp = y + ybase + (size_t)(g*64+ch)*NPOS + (size_t)r8*IMG;
    float4 v0 = *(const float4*)yp;
    float4 v1 = *(const float4*)(yp+4);
    float vals[8] = {v0.x,v0.y,v0.z,v0.w,v1.x,v1.y,v1.z,v1.w};
    float s=0.f, s2=0.f;
    #pragma unroll
    for (int kk=0;kk<8;kk++){ s+=vals[kk]; s2+=vals[kk]*vals[kk]; }
    block_reduce2<8>(s,s2,red);
    float mean = s * (1.f/4096.f);
    float rstd = rsqrtf(s2*(1.f/4096.f) - mean*mean + 1e-5f);
    float nw_ = n1w[g*64+ch], nb_ = n1b[g*64+ch];
    #pragma unroll
    for (int kk=0;kk<8;kk++)
      bufA[ch*65 + r8*8 + kk] = (vals[kk]-mean)*rstd*nw_ + nb_;
    __syncthreads();

    const int sp = t&63, p1 = sp>>3, p2 = sp&7;
    float cv[8];
    s=0.f; s2=0.f;
    #pragma unroll
    for (int kk2=0;kk2<8;kk2++){
      int ch2 = (t>>6)*8 + kk2;
      int c2 = g*64 + ch2;
      const float* wp = cw + c2*9;
      float acc = cb[c2];
      #pragma unroll
      for (int dy=0;dy<3;dy++){
        int yy = p1+dy-1;
        if (yy>=0 && yy<8){
          #pragma unroll
          for (int dx=0;dx<3;dx++){
            int xx = p2+dx-1;
            if (xx>=0 && xx<8) acc = fmaf(wp[dy*3+dx], bufA[ch2*65 + yy*8+xx], acc);
          }
        }
      }
      cv[kk2]=acc; s+=acc; s2+=acc*acc;
    }
    block_reduce2<8>(s,s2,red);
    float mean2 = s*(1.f/4096.f);
    float rstd2 = rsqrtf(s2*(1.f/4096.f) - mean2*mean2 + 1e-5f);
    short8 pk;
    #pragma unroll
    for (int kk2=0;kk2<8;kk2++){
      int ch2 = (t>>6)*8 + kk2;
      int c2 = g*64 + ch2;
      float f = (cv[kk2]-mean2)*rstd2*cnw[c2] + cnb[c2];
      float val = bufA[ch2*65+sp] + gelu_exact(f);
      pk[kk2] = f2b(val);
    }
    *(short8*)&ynT[(size_t)(posb+sp)*768 + g*64 + (t>>6)*8] = pk;
    __syncthreads();
  }
}

// ---------------- K_B: qkv grouped GEMM (MFMA), no LDS ----------------
__global__ __launch_bounds__(256) void k_b(
    const short* __restrict__ ynT,
    const float* __restrict__ qw, const float* __restrict__ qb,
    const float* __restrict__ kw, const float* __restrict__ kb,
    const float* __restrict__ vw, const float* __restrict__ vb,
    short* __restrict__ qG, short* __restrict__ kG, short* __restrict__ vG)
{
  const int g = blockIdx.x, nb = blockIdx.y;
  const int t = threadIdx.x, wv = t>>6, ln = t&63;
  const int l15 = ln&15, kb8 = (ln>>4)*8;

  short8 afr[12][2];
  float bias[12][4];
  #pragma unroll
  for (int mt=0; mt<12; ++mt){
    const float* W  = (mt<4)? qw : ((mt<8)? kw : vw);
    const float* Bb = (mt<4)? qb : ((mt<8)? kb : vb);
    const int mt2 = mt&3;
    const int row = g*64 + mt2*16 + l15;
    #pragma unroll
    for (int ks=0;ks<2;++ks){
      const float* wp = W + row*64 + ks*32 + kb8;
      float4 w0 = *(const float4*)wp;
      float4 w1 = *(const float4*)(wp+4);
      short8 a;
      a[0]=f2b(w0.x); a[1]=f2b(w0.y); a[2]=f2b(w0.z); a[3]=f2b(w0.w);
      a[4]=f2b(w1.x); a[5]=f2b(w1.y); a[6]=f2b(w1.z); a[7]=f2b(w1.w);
      afr[mt][ks]=a;
    }
    #pragma unroll
    for (int r=0;r<4;++r)
      bias[mt][r] = Bb[g*64 + mt2*16 + (ln>>4)*4 + r];
  }

  for (int tile = wv; tile < 32; tile += 4){
    const int pos0 = nb*512 + tile*16;
    const short* bp = ynT + (size_t)(pos0 + l15)*768 + g*64 + kb8;
    short8 b0 = *(const short8*)(bp);
    short8 b1 = *(const short8*)(bp + 32);
    const int pos = pos0 + l15;
    const int wl = pos>>6, nwin = pos&63;
    #pragma unroll
    for (int mt=0; mt<12; ++mt){
      f32x4 acc = {0.f,0.f,0.f,0.f};
      acc = __builtin_amdgcn_mfma_f32_16x16x32_bf16(afr[mt][0], b0, acc, 0,0,0);
      acc = __builtin_amdgcn_mfma_f32_16x16x32_bf16(afr[mt][1], b1, acc, 0,0,0);
      const int mt2 = mt&3;
      #pragma unroll
      for (int r=0;r<4;++r){
        const int hh = (ln>>4)*4 + r;
        float val = acc[r] + bias[mt][r];
        size_t addr = ((size_t)(wl*16 + hh)*48 + 4*g + mt2)*64 + nwin;
        if (mt<4)      qG[addr] = f2b(val * 0.14433756729740643f);
        else if (mt<8) kG[addr] = f2b(val);
        else           vG[addr] = f2b(val);
      }
    }
  }
}

// ---------------- K_CP: fused attention + proj + residual + norm2 partials ----------
// one block per window: 16 waves (one head each), 1024 threads, 128 KB dynamic LDS
__global__ __launch_bounds__(1024) void k_cp(
    const short* __restrict__ qG, const short* __restrict__ kG,
    const short* __restrict__ vG,
    const float* __restrict__ y,
    const float* __restrict__ pw, const float* __restrict__ pb,
    float* __restrict__ out, float* __restrict__ part, int win0)
{
  extern __shared__ short SM[];     // 65536 shorts = 128 KB
  const int t = threadIdx.x;
  const int h = t>>6, ln = t&63;
  const int wl = blockIdx.x;
  const int win = win0 + wl;
  const int b = win>>10, W1=(win>>5)&31, W2=win&31;
  const size_t ybase = (size_t)b*768*(size_t)NPOS + (size_t)(W1*8)*IMG + (W2*8);
  const int l15 = ln&15, c4 = ln>>4, kb8 = c4*8, rbase = c4*4;
  const size_t hbase = (size_t)(wl*16+h)*48;
  short* R = SM + h*4096;           // wave-private 8 KB region

  // ---- S^T = K Q^T (lane-local softmax columns) ----
  short8 kf[3][2], qf[3][2];
  #pragma unroll
  for (int tt=0;tt<3;++tt)
    #pragma unroll
    for (int ks=0;ks<2;++ks){
      kf[tt][ks] = *(const short8*)&kG[(hbase + 16*tt + l15)*64 + ks*32 + kb8];
      qf[tt][ks] = *(const short8*)&qG[(hbase + 16*tt + l15)*64 + ks*32 + kb8];
    }
  f32x4 Su[6];
  const int DTa[6] = {0,1,1,2,2,2};
  const int ETa[6] = {0,0,1,0,1,2};
  #pragma unroll
  for (int u=0;u<6;++u){
    f32x4 acc = {0.f,0.f,0.f,0.f};
    acc = __builtin_amdgcn_mfma_f32_16x16x32_bf16(kf[ETa[u]][0], qf[DTa[u]][0], acc, 0,0,0);
    acc = __builtin_amdgcn_mfma_f32_16x16x32_bf16(kf[ETa[u]][1], qf[DTa[u]][1], acc, 0,0,0);
    Su[u] = acc;
  }

  // ---- masked softmax in-register (unnormalized probs in Su, inv per dt) ----
  float inv3[3];
  #pragma unroll
  for (int dt=0;dt<3;++dt){
    const int ub = (dt==0)?0:((dt==1)?1:3);
    float m = -1e30f;
    #pragma unroll
    for (int et=0; et<=dt; ++et)
      #pragma unroll
      for (int r=0;r<4;++r){
        bool valid = (et<dt) || ((rbase + r) <= (l15|3));
        if (valid) m = fmaxf(m, Su[ub+et][r]);
      }
    m = fmaxf(m, __shfl_xor(m,16));
    m = fmaxf(m, __shfl_xor(m,32));
    float sm = 0.f;
    #pragma unroll
    for (int et=0; et<=dt; ++et)
      #pragma unroll
      for (int r=0;r<4;++r){
        bool valid = (et<dt) || ((rbase + r) <= (l15|3));
        float p = valid ? expf(Su[ub+et][r] - m) : 0.f;
        Su[ub+et][r] = p; sm += p;
      }
    sm += __shfl_xor(sm,16);
    sm += __shfl_xor(sm,32);
    inv3[dt] = 1.f/sm;
  }

  // ---- stage vT into private region (swizzled), read PV B-frags to regs ----
  short8 z8 = {0,0,0,0,0,0,0,0};
  #pragma unroll
  for (int nblk=0;nblk<8;++nblk){
    short8 v8 = z8;
    if (ln < 48) v8 = *(const short8*)&vG[(hbase + ln)*64 + nblk*8];
    #pragma unroll
    for (int j=0;j<8;++j){
      int n = nblk*8 + j;
      R[n*64 + (((ln>>3) ^ (n&7))<<3) + (ln&7)] = v8[j];
    }
  }
  short8 bv[4][2];
  #pragma unroll
  for (int nt=0;nt<4;++nt){
    const int n = 16*nt + l15;
    bv[nt][0] = *(const short8*)&R[n*64 + ((c4 ^ (n&7))<<3)];
    bv[nt][1] = *(const short8*)&R[n*64 + (((4+c4) ^ (n&7))<<3)];
  }

  // ---- overwrite region with P (zero + swizzled scatter), read A-frags ----
  #pragma unroll
  for (int i_=0;i_<6;++i_) *(short8*)&R[i_*512 + ln*8] = z8;
  #pragma unroll
  for (int dt=0;dt<3;++dt){
    const int ub = (dt==0)?0:((dt==1)?1:3);
    const int d = 16*dt + l15;
    #pragma unroll
    for (int et=0; et<=dt; ++et)
      #pragma unroll
      for (int r=0;r<4;++r){
        int e = 16*et + rbase + r;
        R[d*64 + (((e>>3) ^ (d&7))<<3) + (e&7)] = f2b(Su[ub+et][r]*inv3[dt]);
      }
  }
  short8 aP[4];
  const int PDT[4] = {0,1,2,2}, PKS[4] = {0,0,0,1};
  #pragma unroll
  for (int i_=0;i_<4;++i_){
    int d = 16*PDT[i_] + l15;
    int ch = PKS[i_]*4 + c4;
    aP[i_] = *(const short8*)&R[d*64 + ((ch ^ (d&7))<<3)];
  }

  __syncthreads();   // all LDS reads done chip-wide; regions become O-buffer [g][n][ci]

  // ---- PV (reg-only) + store O into group-major swizzled O-buffer ----
  #pragma unroll
  for (int nt=0;nt<4;++nt){
    const int n = 16*nt + l15;
    f32x4 O0 = {0.f,0.f,0.f,0.f};
    f32x4 O1 = {0.f,0.f,0.f,0.f};
    f32x4 O2 = {0.f,0.f,0.f,0.f};
    O0 = __builtin_amdgcn_mfma_f32_16x16x32_bf16(aP[0], bv[nt][0], O0, 0,0,0);
    O1 = __builtin_amdgcn_mfma_f32_16x16x32_bf16(aP[1], bv[nt][0], O1, 0,0,0);
    O2 = __builtin_amdgcn_mfma_f32_16x16x32_bf16(aP[2], bv[nt][0], O2, 0,0,0);
    O2 = __builtin_amdgcn_mfma_f32_16x16x32_bf16(aP[3], bv[nt][1], O2, 0,0,0);
    // d = 16*t_ + rbase + r ; g = 4*t_ + c4 ; ci = (d&3)*16 + h = r*16 + h
    #pragma unroll
    for (int r=0;r<4;++r){
      const int swz = (((2*r + (h>>3)) ^ (n&7))<<3) + (h&7);
      SM[(c4     )*4096 + n*64 + swz] = f2b(O0[r]);
      SM[(4 + c4 )*4096 + n*64 + swz] = f2b(O1[r]);
      SM[(8 + c4 )*4096 + n*64 + swz] = f2b(O2[r]);
    }
  }

  __syncthreads();

  // ---- proj: 48 units (g, mt), 3 per wave ----
  #pragma unroll 1
  for (int j=0;j<3;++j){
    const int u = h*3 + j;
    const int g = u>>2, mt = u&3;
    short8 aw[2];
    float bi[4];
    #pragma unroll
    for (int ks=0;ks<2;++ks){
      const float* wp = pw + (size_t)(g*64 + mt*16 + l15)*64 + ks*32 + kb8;
      float4 w0 = *(const float4*)wp, w1 = *(const float4*)(wp+4);
      short8 a;
      a[0]=f2b(w0.x); a[1]=f2b(w0.y); a[2]=f2b(w0.z); a[3]=f2b(w0.w);
      a[4]=f2b(w1.x); a[5]=f2b(w1.y); a[6]=f2b(w1.z); a[7]=f2b(w1.w);
      aw[ks]=a;
    }
    #pragma unroll
    for (int r=0;r<4;++r) bi[r] = pb[g*64 + mt*16 + rbase + r];

    f32x4 acc[4] = {};
    #pragma unroll
    for (int nt=0;nt<4;++nt){
      const int n = 16*nt + l15;
      short8 b0 = *(const short8*)&SM[g*4096 + n*64 + ((c4 ^ (n&7))<<3)];
      short8 b1 = *(const short8*)&SM[g*4096 + n*64 + (((4+c4) ^ (n&7))<<3)];
      acc[nt] = __builtin_amdgcn_mfma_f32_16x16x32_bf16(aw[0], b0, acc[nt], 0,0,0);
      acc[nt] = __builtin_amdgcn_mfma_f32_16x16x32_bf16(aw[1], b1, acc[nt], 0,0,0);
    }
    float s=0.f, s2=0.f;
    #pragma unroll
    for (int nt=0;nt<4;++nt){
      const int n = 16*nt + l15;
      const size_t rowoff = ybase + (size_t)(n>>3)*IMG + (n&7);
      #pragma unroll
      for (int r=0;r<4;++r){
        int m = mt*16 + rbase + r;
        size_t ad = rowoff + (size_t)(g*64+m)*NPOS;
        float o = y[ad] + bi[r] + acc[nt][r];
        out[ad] = o;
        s += o; s2 += o*o;
      }
    }
    #pragma unroll
    for (int off=32; off>0; off>>=1){ s += __shfl_xor(s, off); s2 += __shfl_xor(s2, off); }
    if (ln==0){
      size_t idx = ((size_t)(b*12+g)*1024 + (win&1023))*4 + mt;
      part[idx*2+0]=s; part[idx*2+1]=s2;
    }
  }
}

// ---------------- K3: finalize norm2 stats (deterministic) ----------------
__global__ __launch_bounds__(256) void k3_stats(
    const float* __restrict__ part, float* __restrict__ stats)
{
  const int bg = blockIdx.x;  // 0..23
  const int t = threadIdx.x;
  float s=0.f, s2=0.f;
  #pragma unroll
  for (int j=0;j<16;++j){
    size_t idx = (size_t)bg*4096 + t*16 + j;
    s  += part[idx*2+0];
    s2 += part[idx*2+1];
  }
  __shared__ float red[10];
  block_reduce2<4>(s,s2,red);
  if (t==0){
    const float Ninv = 1.f/(64.f*65536.f);
    float mean = s*Ninv;
    float var  = s2*Ninv - mean*mean;
    stats[bg*2+0] = mean;
    stats[bg*2+1] = rsqrtf(var + 1e-5f);
  }
}

// ---------------- K_D: norm2 + f1 + gelu + f2 + residual (MFMA, in-place) ----------
__global__ __launch_bounds__(256) void k_d(
    const float* __restrict__ n2w, const float* __restrict__ n2b,
    const float* __restrict__ f1w, const float* __restrict__ f1b,
    const float* __restrict__ f2w, const float* __restrict__ f2bi,
    const float* __restrict__ stats, float* __restrict__ io)
{
  __shared__ short Xb[4096];
  __shared__ short Hb[4096];
  const int t = threadIdx.x;
  const int pt = blockIdx.x, g = blockIdx.y, b = blockIdx.z;
  const int bg = b*12 + g;
  const float mean = stats[bg*2+0], rstd = stats[bg*2+1];
  const size_t base = ((size_t)(b*768 + g*64))*NPOS + (size_t)pt*64;

  {
    const int pp = t>>3, posq = t&7;
    const int ch0 = pp*2;
    const float* p0 = io + base + (size_t)ch0*NPOS + posq*8;
    float4 x00 = *(const float4*)p0;
    float4 x01 = *(const float4*)(p0+4);
    const float* p1 = p0 + NPOS;
    float4 x10 = *(const float4*)p1;
    float4 x11 = *(const float4*)(p1+4);
    float A0 = rstd*n2w[g*64+ch0],   C0 = n2b[g*64+ch0]   - mean*A0;
    float A1 = rstd*n2w[g*64+ch0+1], C1 = n2b[g*64+ch0+1] - mean*A1;
    float va[8] = {x00.x,x00.y,x00.z,x00.w,x01.x,x01.y,x01.z,x01.w};
    float vb[8] = {x10.x,x10.y,x10.z,x10.w,x11.x,x11.y,x11.z,x11.w};
    #pragma unroll
    for (int j=0;j<8;++j){
      int pos = posq*8 + j;
      unsigned int u0 = (unsigned short)f2b(va[j]*A0 + C0);
      unsigned int u1 = (unsigned short)f2b(vb[j]*A1 + C1);
      *(unsigned int*)&Xb[pos*64 + (((ch0>>3) ^ (pos&7))<<3) + (ch0&7)] = u0 | (u1<<16);
    }
  }
  __syncthreads();

  const int wv = t>>6, ln = t&63;
  const int l15 = ln&15, kb8 = (ln>>4)*8, rbase = (ln>>4)*4, c4 = ln>>4;
  const int n = wv*16 + l15;

  short8 af[4][2];
  #pragma unroll
  for (int mt=0;mt<4;++mt)
    #pragma unroll
    for (int ks=0;ks<2;++ks){
      const float* wp = f1w + (size_t)(g*64 + mt*16 + l15)*64 + ks*32 + kb8;
      float4 w0 = *(const float4*)wp, w1 = *(const float4*)(wp+4);
      short8 a;
      a[0]=f2b(w0.x); a[1]=f2b(w0.y); a[2]=f2b(w0.z); a[3]=f2b(w0.w);
      a[4]=f2b(w1.x); a[5]=f2b(w1.y); a[6]=f2b(w1.z); a[7]=f2b(w1.w);
      af[mt][ks]=a;
    }
  f32x4 h[4] = {};
  #pragma unroll
  for (int ks=0;ks<2;++ks){
    short8 bfr = *(const short8*)&Xb[n*64 + (((ks*4 + c4) ^ (n&7))<<3)];
    #pragma unroll
    for (int mt=0;mt<4;++mt)
      h[mt] = __builtin_amdgcn_mfma_f32_16x16x32_bf16(af[mt][ks], bfr, h[mt], 0,0,0);
  }
  #pragma unroll
  for (int mt=0;mt<4;++mt){
    #pragma unroll
    for (int rp=0;rp<4;rp+=2){
      int m = mt*16 + rbase + rp;
      float h0 = gelu_exact(h[mt][rp]   + f1b[g*64+m]);
      float h1 = gelu_exact(h[mt][rp+1] + f1b[g*64+m+1]);
      unsigned int u0 = (unsigned short)f2b(h0);
      unsigned int u1 = (unsigned short)f2b(h1);
      *(unsigned int*)&Hb[n*64 + (((m>>3) ^ (n&7))<<3) + (m&7)] = u0 | (u1<<16);
    }
  }
  __syncthreads();

  #pragma unroll
  for (int mt=0;mt<4;++mt)
    #pragma unroll
    for (int ks=0;ks<2;++ks){
      const float* wp = f2w + (size_t)(g*64 + mt*16 + l15)*64 + ks*32 + kb8;
      float4 w0 = *(const float4*)wp, w1 = *(const float4*)(wp+4);
      short8 a;
      a[0]=f2b(w0.x); a[1]=f2b(w0.y); a[2]=f2b(w0.z); a[3]=f2b(w0.w);
      a[4]=f2b(w1.x); a[5]=f2b(w1.y); a[6]=f2b(w1.z); a[7]=f2b(w1.w);
      af[mt][ks]=a;
    }
  f32x4 o[4] = {};
  #pragma unroll
  for (int ks=0;ks<2;++ks){
    short8 bfr = *(const short8*)&Hb[n*64 + (((ks*4 + c4) ^ (n&7))<<3)];
    #pragma unroll
    for (int mt=0;mt<4;++mt)
      o[mt] = __builtin_amdgcn_mfma_f32_16x16x32_bf16(af[mt][ks], bfr, o[mt], 0,0,0);
  }
  #pragma unroll
  for (int mt=0;mt<4;++mt)
    #pragma unroll
    for (int r=0;r<4;++r){
      int m = mt*16 + rbase + r;
      float* op = io + base + (size_t)m*NPOS + n;
      *op = *op + o[mt][r] + f2bi[g*64+m];
    }
}

extern "C" void kernel_launch(void* const* d_in, const int* in_sizes, int n_in,
                              void* d_out, int out_size, void* d_ws, size_t ws_size,
                              hipStream_t stream){
  const float* y    = (const float*)d_in[0];
  const float* n1w  = (const float*)d_in[1];
  const float* n1b  = (const float*)d_in[2];
  const float* cw   = (const float*)d_in[3];
  const float* cb   = (const float*)d_in[4];
  const float* cnw  = (const float*)d_in[5];
  const float* cnb  = (const float*)d_in[6];
  const float* qw   = (const float*)d_in[7];
  const float* qb   = (const float*)d_in[8];
  const float* kw   = (const float*)d_in[9];
  const float* kb   = (const float*)d_in[10];
  const float* vw   = (const float*)d_in[11];
  const float* vb   = (const float*)d_in[12];
  const float* pw   = (const float*)d_in[13];
  const float* pb   = (const float*)d_in[14];
  const float* n2w  = (const float*)d_in[15];
  const float* n2b  = (const float*)d_in[16];
  const float* f1w  = (const float*)d_in[17];
  const float* f1b  = (const float*)d_in[18];
  const float* f2w  = (const float*)d_in[19];
  const float* f2b_ = (const float*)d_in[20];
  float* out   = (float*)d_out;

  unsigned char* wsb = (unsigned char*)d_ws;
  float* part  = (float*)wsb;                 // 24*1024*4*2 f32 = 786 KB
  float* stats = part + 24*1024*4*2;          // 48 f32

  // adaptive chunking: 4 buffers (ynT, q, k, v) of Y bytes each
  int C = 32;
  {
    const int cand[6] = {1,2,4,8,16,32};
    for (int i=0;i<6;++i){
      int nw = 2048 / cand[i];
      size_t Y = (size_t)nw * 64 * 768 * 2;
      if ((size_t)(1<<20) + 4*Y <= ws_size){ C = cand[i]; break; }
    }
  }
  const int nw = 2048 / C;
  const size_t Y = (size_t)nw * 64 * 768 * 2;
  short* ynT = (short*)(wsb + (1<<20));
  short* qG  = (short*)(wsb + (1<<20) + Y);
  short* kG  = (short*)(wsb + (1<<20) + 2*Y);
  short* vG  = (short*)(wsb + (1<<20) + 3*Y);

  for (int c=0; c<C; ++c){
    int win0 = c * nw;
    hipLaunchKernelGGL(k_a, dim3(nw), dim3(512), 0, stream,
                       y, n1w,n1b, cw,cb, cnw,cnb, ynT, win0);
    hipLaunchKernelGGL(k_b, dim3(12, nw/8), dim3(256), 0, stream,
                       ynT, qw,qb, kw,kb, vw,vb, qG, kG, vG);
    hipLaunchKernelGGL(k_cp, dim3(nw), dim3(1024), 131072, stream,
                       qG, kG, vG, y, pw, pb, out, part, win0);
  }
  hipLaunchKernelGGL(k3_stats, dim3(24), dim3(256), 0, stream, part, stats);
  hipLaunchKernelGGL(k_d, dim3(1024, 12, 2), dim3(256), 0, stream,
                     n2w,n2b, f1w,f1b, f2w,f2b_, stats, out);
}

// Round 6
// 1895.646 us; speedup vs baseline: 3.3451x; 1.0647x over previous
//
#include <hip/hip_runtime.h>
#include <hip/hip_bf16.h>

#define IMG 256
#define NPOS 65536

typedef __attribute__((ext_vector_type(8))) short short8;
typedef __attribute__((ext_vector_type(4))) float f32x4;

__device__ __forceinline__ float gelu_exact(float x){
  return 0.5f * x * (1.0f + erff(x * 0.7071067811865475f));
}

__device__ __forceinline__ short f2b(float x){
  __hip_bfloat16 hh = __float2bfloat16(x);
  short s;
  __builtin_memcpy(&s, &hh, sizeof(s));
  return s;
}

template<int NWAVES>
__device__ __forceinline__ void block_reduce2(float& s, float& s2, float* red){
  __syncthreads();  // protect red[] reuse from previous call
  #pragma unroll
  for (int off=32; off>0; off>>=1){ s += __shfl_down(s, off); s2 += __shfl_down(s2, off); }
  int lane = threadIdx.x & 63, w = threadIdx.x >> 6;
  if (lane==0){ red[w*2]=s; red[w*2+1]=s2; }
  __syncthreads();
  if (threadIdx.x==0){
    float a=0.f, bb=0.f;
    #pragma unroll
    for (int i=0;i<NWAVES;i++){ a+=red[i*2]; bb+=red[i*2+1]; }
    red[2*NWAVES]=a; red[2*NWAVES+1]=bb;
  }
  __syncthreads();
  s=red[2*NWAVES]; s2=red[2*NWAVES+1];
}

// ---------------- W_CVT: f32 -> bf16 weights, once per launch ----------------
__global__ __launch_bounds__(1024) void w_cvt(
    const float* __restrict__ w0, const float* __restrict__ w1,
    const float* __restrict__ w2, const float* __restrict__ w3,
    const float* __restrict__ w4, const float* __restrict__ w5,
    short* __restrict__ outw)
{
  const int mi = blockIdx.y;
  const float* src = mi==0?w0: mi==1?w1: mi==2?w2: mi==3?w3: mi==4?w4: w5;
  const int i = blockIdx.x*1024 + threadIdx.x;
  outw[(size_t)mi*49152 + i] = f2b(src[i]);
}

// ---------------- K_A: norm1 + CPE -> ynT bf16 [pos_local][768] ----------------
__global__ __launch_bounds__(512) void k_a(
    const float* __restrict__ y,
    const float* __restrict__ n1w, const float* __restrict__ n1b,
    const float* __restrict__ cw,  const float* __restrict__ cb,
    const float* __restrict__ cnw, const float* __restrict__ cnb,
    short* __restrict__ ynT, int win0)
{
  __shared__ float bufA[64*65];   // +1 pad
  __shared__ float red[18];
  const int t = threadIdx.x;
  const int win = win0 + blockIdx.x;
  const int b = win >> 10, W1 = (win>>5)&31, W2 = win&31;
  const size_t ybase = (size_t)b*768*(size_t)NPOS + (size_t)(W1*8)*IMG + (W2*8);
  const int posb = blockIdx.x * 64;

  for (int g=0; g<12; ++g){
    const int ch = t>>3, r8 = t&7;
    const float* yp = y + ybase + (size_t)(g*64+ch)*NPOS + (size_t)r8*IMG;
    float4 v0 = *(const float4*)yp;
    float4 v1 = *(const float4*)(yp+4);
    float vals[8] = {v0.x,v0.y,v0.z,v0.w,v1.x,v1.y,v1.z,v1.w};
    float s=0.f, s2=0.f;
    #pragma unroll
    for (int kk=0;kk<8;kk++){ s+=vals[kk]; s2+=vals[kk]*vals[kk]; }
    block_reduce2<8>(s,s2,red);
    float mean = s * (1.f/4096.f);
    float rstd = rsqrtf(s2*(1.f/4096.f) - mean*mean + 1e-5f);
    float nw_ = n1w[g*64+ch], nb_ = n1b[g*64+ch];
    #pragma unroll
    for (int kk=0;kk<8;kk++)
      bufA[ch*65 + r8*8 + kk] = (vals[kk]-mean)*rstd*nw_ + nb_;
    __syncthreads();

    const int sp = t&63, p1 = sp>>3, p2 = sp&7;
    float cv[8];
    s=0.f; s2=0.f;
    #pragma unroll
    for (int kk2=0;kk2<8;kk2++){
      int ch2 = (t>>6)*8 + kk2;
      int c2 = g*64 + ch2;
      const float* wp = cw + c2*9;
      float acc = cb[c2];
      #pragma unroll
      for (int dy=0;dy<3;dy++){
        int yy = p1+dy-1;
        if (yy>=0 && yy<8){
          #pragma unroll
          for (int dx=0;dx<3;dx++){
            int xx = p2+dx-1;
            if (xx>=0 && xx<8) acc = fmaf(wp[dy*3+dx], bufA[ch2*65 + yy*8+xx], acc);
          }
        }
      }
      cv[kk2]=acc; s+=acc; s2+=acc*acc;
    }
    block_reduce2<8>(s,s2,red);
    float mean2 = s*(1.f/4096.f);
    float rstd2 = rsqrtf(s2*(1.f/4096.f) - mean2*mean2 + 1e-5f);
    short8 pk;
    #pragma unroll
    for (int kk2=0;kk2<8;kk2++){
      int ch2 = (t>>6)*8 + kk2;
      int c2 = g*64 + ch2;
      float f = (cv[kk2]-mean2)*rstd2*cnw[c2] + cnb[c2];
      float val = bufA[ch2*65+sp] + gelu_exact(f);
      pk[kk2] = f2b(val);
    }
    *(short8*)&ynT[(size_t)(posb+sp)*768 + g*64 + (t>>6)*8] = pk;
    __syncthreads();
  }
}

// ---------------- K_B: qkv grouped GEMM (MFMA), no LDS, bf16 weights ----------------
__global__ __launch_bounds__(256) void k_b(
    const short* __restrict__ ynT,
    const short* __restrict__ qwB, const float* __restrict__ qb,
    const short* __restrict__ kwB, const float* __restrict__ kb,
    const short* __restrict__ vwB, const float* __restrict__ vb,
    short* __restrict__ qG, short* __restrict__ kG, short* __restrict__ vG)
{
  const int g = blockIdx.x, nb = blockIdx.y;
  const int t = threadIdx.x, wv = t>>6, ln = t&63;
  const int l15 = ln&15, kb8 = (ln>>4)*8;

  short8 afr[12][2];
  float bias[12][4];
  #pragma unroll
  for (int mt=0; mt<12; ++mt){
    const short* WB = (mt<4)? qwB : ((mt<8)? kwB : vwB);
    const float* Bb = (mt<4)? qb : ((mt<8)? kb : vb);
    const int mt2 = mt&3;
    const int row = g*64 + mt2*16 + l15;
    #pragma unroll
    for (int ks=0;ks<2;++ks)
      afr[mt][ks] = *(const short8*)&WB[(size_t)row*64 + ks*32 + kb8];
    #pragma unroll
    for (int r=0;r<4;++r)
      bias[mt][r] = Bb[g*64 + mt2*16 + (ln>>4)*4 + r];
  }

  for (int tile = wv; tile < 32; tile += 4){
    const int pos0 = nb*512 + tile*16;
    const short* bp = ynT + (size_t)(pos0 + l15)*768 + g*64 + kb8;
    short8 b0 = *(const short8*)(bp);
    short8 b1 = *(const short8*)(bp + 32);
    const int pos = pos0 + l15;
    const int wl = pos>>6, nwin = pos&63;
    #pragma unroll
    for (int mt=0; mt<12; ++mt){
      f32x4 acc = {0.f,0.f,0.f,0.f};
      acc = __builtin_amdgcn_mfma_f32_16x16x32_bf16(afr[mt][0], b0, acc, 0,0,0);
      acc = __builtin_amdgcn_mfma_f32_16x16x32_bf16(afr[mt][1], b1, acc, 0,0,0);
      const int mt2 = mt&3;
      #pragma unroll
      for (int r=0;r<4;++r){
        const int hh = (ln>>4)*4 + r;
        float val = acc[r] + bias[mt][r];
        size_t addr = ((size_t)(wl*16 + hh)*48 + 4*g + mt2)*64 + nwin;
        if (mt<4)      qG[addr] = f2b(val * 0.14433756729740643f);
        else if (mt<8) kG[addr] = f2b(val);
        else           vG[addr] = f2b(val);
      }
    }
  }
}

// ---------------- K_CP: fused attention + proj + residual + norm2 partials ----------
// one block per window: 16 waves (one head each), 1024 threads, 128 KB dynamic LDS
__global__ __launch_bounds__(1024) void k_cp(
    const short* __restrict__ qG, const short* __restrict__ kG,
    const short* __restrict__ vG,
    const float* __restrict__ y,
    const short* __restrict__ pwB, const float* __restrict__ pb,
    float* __restrict__ out, float* __restrict__ part, int win0)
{
  extern __shared__ short SM[];     // 65536 shorts = 128 KB
  const int t = threadIdx.x;
  const int h = t>>6, ln = t&63;
  const int wl = blockIdx.x;
  const int win = win0 + wl;
  const int b = win>>10, W1=(win>>5)&31, W2=win&31;
  const size_t ybase = (size_t)b*768*(size_t)NPOS + (size_t)(W1*8)*IMG + (W2*8);
  const int l15 = ln&15, c4 = ln>>4, kb8 = c4*8, rbase = c4*4;
  const size_t hbase = (size_t)(wl*16+h)*48;
  short* R = SM + h*4096;           // wave-private 8 KB region

  // ---- prefetch residual y values for this thread's proj units (hides HBM latency) ----
  float yres[3][16];
  #pragma unroll
  for (int j=0;j<3;++j){
    const int u = h*3 + j;
    const int g = u>>2, mt = u&3;
    #pragma unroll
    for (int nt=0;nt<4;++nt){
      const int n = 16*nt + l15;
      const size_t rowoff = ybase + (size_t)(n>>3)*IMG + (n&7);
      #pragma unroll
      for (int r=0;r<4;++r)
        yres[j][nt*4+r] = y[rowoff + (size_t)(g*64 + mt*16 + rbase + r)*NPOS];
    }
  }

  // ---- S^T = K Q^T (lane-local softmax columns) ----
  short8 kf[3][2], qf[3][2];
  #pragma unroll
  for (int tt=0;tt<3;++tt)
    #pragma unroll
    for (int ks=0;ks<2;++ks){
      kf[tt][ks] = *(const short8*)&kG[(hbase + 16*tt + l15)*64 + ks*32 + kb8];
      qf[tt][ks] = *(const short8*)&qG[(hbase + 16*tt + l15)*64 + ks*32 + kb8];
    }
  f32x4 Su[6];
  const int DTa[6] = {0,1,1,2,2,2};
  const int ETa[6] = {0,0,1,0,1,2};
  #pragma unroll
  for (int u=0;u<6;++u){
    f32x4 acc = {0.f,0.f,0.f,0.f};
    acc = __builtin_amdgcn_mfma_f32_16x16x32_bf16(kf[ETa[u]][0], qf[DTa[u]][0], acc, 0,0,0);
    acc = __builtin_amdgcn_mfma_f32_16x16x32_bf16(kf[ETa[u]][1], qf[DTa[u]][1], acc, 0,0,0);
    Su[u] = acc;
  }

  // ---- masked softmax in-register (unnormalized probs in Su, inv per dt) ----
  float inv3[3];
  #pragma unroll
  for (int dt=0;dt<3;++dt){
    const int ub = (dt==0)?0:((dt==1)?1:3);
    float m = -1e30f;
    #pragma unroll
    for (int et=0; et<=dt; ++et)
      #pragma unroll
      for (int r=0;r<4;++r){
        bool valid = (et<dt) || ((rbase + r) <= (l15|3));
        if (valid) m = fmaxf(m, Su[ub+et][r]);
      }
    m = fmaxf(m, __shfl_xor(m,16));
    m = fmaxf(m, __shfl_xor(m,32));
    float sm = 0.f;
    #pragma unroll
    for (int et=0; et<=dt; ++et)
      #pragma unroll
      for (int r=0;r<4;++r){
        bool valid = (et<dt) || ((rbase + r) <= (l15|3));
        float p = valid ? expf(Su[ub+et][r] - m) : 0.f;
        Su[ub+et][r] = p; sm += p;
      }
    sm += __shfl_xor(sm,16);
    sm += __shfl_xor(sm,32);
    inv3[dt] = 1.f/sm;
  }

  // ---- stage vT into private region (swizzled), read PV B-frags to regs ----
  short8 z8 = {0,0,0,0,0,0,0,0};
  #pragma unroll
  for (int nblk=0;nblk<8;++nblk){
    short8 v8 = z8;
    if (ln < 48) v8 = *(const short8*)&vG[(hbase + ln)*64 + nblk*8];
    #pragma unroll
    for (int j=0;j<8;++j){
      int n = nblk*8 + j;
      R[n*64 + (((ln>>3) ^ (n&7))<<3) + (ln&7)] = v8[j];
    }
  }
  short8 bv[4][2];
  #pragma unroll
  for (int nt=0;nt<4;++nt){
    const int n = 16*nt + l15;
    bv[nt][0] = *(const short8*)&R[n*64 + ((c4 ^ (n&7))<<3)];
    bv[nt][1] = *(const short8*)&R[n*64 + (((4+c4) ^ (n&7))<<3)];
  }

  // ---- overwrite region with P (zero + swizzled scatter), read A-frags ----
  #pragma unroll
  for (int i_=0;i_<6;++i_) *(short8*)&R[i_*512 + ln*8] = z8;
  #pragma unroll
  for (int dt=0;dt<3;++dt){
    const int ub = (dt==0)?0:((dt==1)?1:3);
    const int d = 16*dt + l15;
    #pragma unroll
    for (int et=0; et<=dt; ++et)
      #pragma unroll
      for (int r=0;r<4;++r){
        int e = 16*et + rbase + r;
        R[d*64 + (((e>>3) ^ (d&7))<<3) + (e&7)] = f2b(Su[ub+et][r]*inv3[dt]);
      }
  }
  short8 aP[4];
  const int PDT[4] = {0,1,2,2}, PKS[4] = {0,0,0,1};
  #pragma unroll
  for (int i_=0;i_<4;++i_){
    int d = 16*PDT[i_] + l15;
    int ch = PKS[i_]*4 + c4;
    aP[i_] = *(const short8*)&R[d*64 + ((ch ^ (d&7))<<3)];
  }

  __syncthreads();   // all LDS reads done; regions become O-buffer [g][n][ci]

  // ---- PV (reg-only) + store O into group-major swizzled O-buffer ----
  #pragma unroll
  for (int nt=0;nt<4;++nt){
    const int n = 16*nt + l15;
    f32x4 O0 = {0.f,0.f,0.f,0.f};
    f32x4 O1 = {0.f,0.f,0.f,0.f};
    f32x4 O2 = {0.f,0.f,0.f,0.f};
    O0 = __builtin_amdgcn_mfma_f32_16x16x32_bf16(aP[0], bv[nt][0], O0, 0,0,0);
    O1 = __builtin_amdgcn_mfma_f32_16x16x32_bf16(aP[1], bv[nt][0], O1, 0,0,0);
    O2 = __builtin_amdgcn_mfma_f32_16x16x32_bf16(aP[2], bv[nt][0], O2, 0,0,0);
    O2 = __builtin_amdgcn_mfma_f32_16x16x32_bf16(aP[3], bv[nt][1], O2, 0,0,0);
    #pragma unroll
    for (int r=0;r<4;++r){
      const int swz = (((2*r + (h>>3)) ^ (n&7))<<3) + (h&7);
      SM[(c4     )*4096 + n*64 + swz] = f2b(O0[r]);
      SM[(4 + c4 )*4096 + n*64 + swz] = f2b(O1[r]);
      SM[(8 + c4 )*4096 + n*64 + swz] = f2b(O2[r]);
    }
  }

  __syncthreads();

  // ---- proj: 48 units (g, mt), 3 per wave (fully unrolled for static yres idx) ----
  #pragma unroll
  for (int j=0;j<3;++j){
    const int u = h*3 + j;
    const int g = u>>2, mt = u&3;
    short8 aw[2];
    float bi[4];
    #pragma unroll
    for (int ks=0;ks<2;++ks)
      aw[ks] = *(const short8*)&pwB[(size_t)(g*64 + mt*16 + l15)*64 + ks*32 + kb8];
    #pragma unroll
    for (int r=0;r<4;++r) bi[r] = pb[g*64 + mt*16 + rbase + r];

    f32x4 acc[4] = {};
    #pragma unroll
    for (int nt=0;nt<4;++nt){
      const int n = 16*nt + l15;
      short8 b0 = *(const short8*)&SM[g*4096 + n*64 + ((c4 ^ (n&7))<<3)];
      short8 b1 = *(const short8*)&SM[g*4096 + n*64 + (((4+c4) ^ (n&7))<<3)];
      acc[nt] = __builtin_amdgcn_mfma_f32_16x16x32_bf16(aw[0], b0, acc[nt], 0,0,0);
      acc[nt] = __builtin_amdgcn_mfma_f32_16x16x32_bf16(aw[1], b1, acc[nt], 0,0,0);
    }
    float s=0.f, s2=0.f;
    #pragma unroll
    for (int nt=0;nt<4;++nt){
      const int n = 16*nt + l15;
      const size_t rowoff = ybase + (size_t)(n>>3)*IMG + (n&7);
      #pragma unroll
      for (int r=0;r<4;++r){
        int m = mt*16 + rbase + r;
        size_t ad = rowoff + (size_t)(g*64+m)*NPOS;
        float o = yres[j][nt*4+r] + bi[r] + acc[nt][r];
        out[ad] = o;
        s += o; s2 += o*o;
      }
    }
    #pragma unroll
    for (int off=32; off>0; off>>=1){ s += __shfl_xor(s, off); s2 += __shfl_xor(s2, off); }
    if (ln==0){
      size_t idx = ((size_t)(b*12+g)*1024 + (win&1023))*4 + mt;
      part[idx*2+0]=s; part[idx*2+1]=s2;
    }
  }
}

// ---------------- K3: finalize norm2 stats (deterministic) ----------------
__global__ __launch_bounds__(256) void k3_stats(
    const float* __restrict__ part, float* __restrict__ stats)
{
  const int bg = blockIdx.x;  // 0..23
  const int t = threadIdx.x;
  float s=0.f, s2=0.f;
  #pragma unroll
  for (int j=0;j<16;++j){
    size_t idx = (size_t)bg*4096 + t*16 + j;
    s  += part[idx*2+0];
    s2 += part[idx*2+1];
  }
  __shared__ float red[10];
  block_reduce2<4>(s,s2,red);
  if (t==0){
    const float Ninv = 1.f/(64.f*65536.f);
    float mean = s*Ninv;
    float var  = s2*Ninv - mean*mean;
    stats[bg*2+0] = mean;
    stats[bg*2+1] = rsqrtf(var + 1e-5f);
  }
}

// ---------------- K_D: norm2 + f1 + gelu + f2 + residual (MFMA, in-place) ----------
__global__ __launch_bounds__(256) void k_d(
    const float* __restrict__ n2w, const float* __restrict__ n2b,
    const short* __restrict__ f1wB, const float* __restrict__ f1b,
    const short* __restrict__ f2wB, const float* __restrict__ f2bi,
    const float* __restrict__ stats, float* __restrict__ io)
{
  __shared__ short Xb[4096];
  __shared__ short Hb[4096];
  const int t = threadIdx.x;
  const int pt = blockIdx.x, g = blockIdx.y, b = blockIdx.z;
  const int bg = b*12 + g;
  const float mean = stats[bg*2+0], rstd = stats[bg*2+1];
  const size_t base = ((size_t)(b*768 + g*64))*NPOS + (size_t)pt*64;

  const int wv = t>>6, ln = t&63;
  const int l15 = ln&15, kb8 = (ln>>4)*8, rbase = (ln>>4)*4, c4 = ln>>4;
  const int n = wv*16 + l15;

  // prefetch final-residual values (store-phase mapping) — overlaps MFMA phases
  float res[16];
  #pragma unroll
  for (int mt=0;mt<4;++mt)
    #pragma unroll
    for (int r=0;r<4;++r)
      res[mt*4+r] = io[base + (size_t)(mt*16 + rbase + r)*NPOS + n];

  {
    const int pp = t>>3, posq = t&7;
    const int ch0 = pp*2;
    const float* p0 = io + base + (size_t)ch0*NPOS + posq*8;
    float4 x00 = *(const float4*)p0;
    float4 x01 = *(const float4*)(p0+4);
    const float* p1 = p0 + NPOS;
    float4 x10 = *(const float4*)p1;
    float4 x11 = *(const float4*)(p1+4);
    float A0 = rstd*n2w[g*64+ch0],   C0 = n2b[g*64+ch0]   - mean*A0;
    float A1 = rstd*n2w[g*64+ch0+1], C1 = n2b[g*64+ch0+1] - mean*A1;
    float va[8] = {x00.x,x00.y,x00.z,x00.w,x01.x,x01.y,x01.z,x01.w};
    float vb[8] = {x10.x,x10.y,x10.z,x10.w,x11.x,x11.y,x11.z,x11.w};
    #pragma unroll
    for (int j=0;j<8;++j){
      int pos = posq*8 + j;
      unsigned int u0 = (unsigned short)f2b(va[j]*A0 + C0);
      unsigned int u1 = (unsigned short)f2b(vb[j]*A1 + C1);
      *(unsigned int*)&Xb[pos*64 + (((ch0>>3) ^ (pos&7))<<3) + (ch0&7)] = u0 | (u1<<16);
    }
  }
  __syncthreads();

  short8 af[4][2];
  #pragma unroll
  for (int mt=0;mt<4;++mt)
    #pragma unroll
    for (int ks=0;ks<2;++ks)
      af[mt][ks] = *(const short8*)&f1wB[(size_t)(g*64 + mt*16 + l15)*64 + ks*32 + kb8];
  f32x4 h[4] = {};
  #pragma unroll
  for (int ks=0;ks<2;++ks){
    short8 bfr = *(const short8*)&Xb[n*64 + (((ks*4 + c4) ^ (n&7))<<3)];
    #pragma unroll
    for (int mt=0;mt<4;++mt)
      h[mt] = __builtin_amdgcn_mfma_f32_16x16x32_bf16(af[mt][ks], bfr, h[mt], 0,0,0);
  }
  #pragma unroll
  for (int mt=0;mt<4;++mt){
    #pragma unroll
    for (int rp=0;rp<4;rp+=2){
      int m = mt*16 + rbase + rp;
      float h0 = gelu_exact(h[mt][rp]   + f1b[g*64+m]);
      float h1 = gelu_exact(h[mt][rp+1] + f1b[g*64+m+1]);
      unsigned int u0 = (unsigned short)f2b(h0);
      unsigned int u1 = (unsigned short)f2b(h1);
      *(unsigned int*)&Hb[n*64 + (((m>>3) ^ (n&7))<<3) + (m&7)] = u0 | (u1<<16);
    }
  }
  __syncthreads();

  #pragma unroll
  for (int mt=0;mt<4;++mt)
    #pragma unroll
    for (int ks=0;ks<2;++ks)
      af[mt][ks] = *(const short8*)&f2wB[(size_t)(g*64 + mt*16 + l15)*64 + ks*32 + kb8];
  f32x4 o[4] = {};
  #pragma unroll
  for (int ks=0;ks<2;++ks){
    short8 bfr = *(const short8*)&Hb[n*64 + (((ks*4 + c4) ^ (n&7))<<3)];
    #pragma unroll
    for (int mt=0;mt<4;++mt)
      o[mt] = __builtin_amdgcn_mfma_f32_16x16x32_bf16(af[mt][ks], bfr, o[mt], 0,0,0);
  }
  #pragma unroll
  for (int mt=0;mt<4;++mt)
    #pragma unroll
    for (int r=0;r<4;++r){
      int m = mt*16 + rbase + r;
      io[base + (size_t)m*NPOS + n] = res[mt*4+r] + o[mt][r] + f2bi[g*64+m];
    }
}

extern "C" void kernel_launch(void* const* d_in, const int* in_sizes, int n_in,
                              void* d_out, int out_size, void* d_ws, size_t ws_size,
                              hipStream_t stream){
  const float* y    = (const float*)d_in[0];
  const float* n1w  = (const float*)d_in[1];
  const float* n1b  = (const float*)d_in[2];
  const float* cw   = (const float*)d_in[3];
  const float* cb   = (const float*)d_in[4];
  const float* cnw  = (const float*)d_in[5];
  const float* cnb  = (const float*)d_in[6];
  const float* qw   = (const float*)d_in[7];
  const float* qb   = (const float*)d_in[8];
  const float* kw   = (const float*)d_in[9];
  const float* kb   = (const float*)d_in[10];
  const float* vw   = (const float*)d_in[11];
  const float* vb   = (const float*)d_in[12];
  const float* pw   = (const float*)d_in[13];
  const float* pb   = (const float*)d_in[14];
  const float* n2w  = (const float*)d_in[15];
  const float* n2b  = (const float*)d_in[16];
  const float* f1w  = (const float*)d_in[17];
  const float* f1b  = (const float*)d_in[18];
  const float* f2w  = (const float*)d_in[19];
  const float* f2b_ = (const float*)d_in[20];
  float* out   = (float*)d_out;

  unsigned char* wsb = (unsigned char*)d_ws;
  float* part  = (float*)wsb;                 // 24*1024*4*2 f32 = 786432 B
  float* stats = part + 24*1024*4*2;          // 48 f32 -> ends 786624
  short* wbf   = (short*)(wsb + 786624);      // 6 * 49152 bf16 = 589824 B
  short* qwB  = wbf;
  short* kwB  = wbf + 49152;
  short* vwB  = wbf + 2*49152;
  short* pwB  = wbf + 3*49152;
  short* f1wB = wbf + 4*49152;
  short* f2wB = wbf + 5*49152;

  // adaptive chunking: 4 buffers (ynT, q, k, v) of Y bytes each, from 2 MB offset
  int C = 32;
  {
    const int cand[6] = {1,2,4,8,16,32};
    for (int i=0;i<6;++i){
      int nw = 2048 / cand[i];
      size_t Y = (size_t)nw * 64 * 768 * 2;
      if ((size_t)(1<<21) + 4*Y <= ws_size){ C = cand[i]; break; }
    }
  }
  const int nw = 2048 / C;
  const size_t Y = (size_t)nw * 64 * 768 * 2;
  short* ynT = (short*)(wsb + (1<<21));
  short* qG  = (short*)(wsb + (1<<21) + Y);
  short* kG  = (short*)(wsb + (1<<21) + 2*Y);
  short* vG  = (short*)(wsb + (1<<21) + 3*Y);

  hipLaunchKernelGGL(w_cvt, dim3(48, 6), dim3(1024), 0, stream,
                     qw, kw, vw, pw, f1w, f2w, wbf);

  for (int c=0; c<C; ++c){
    int win0 = c * nw;
    hipLaunchKernelGGL(k_a, dim3(nw), dim3(512), 0, stream,
                       y, n1w,n1b, cw,cb, cnw,cnb, ynT, win0);
    hipLaunchKernelGGL(k_b, dim3(12, nw/8), dim3(256), 0, stream,
                       ynT, qwB,qb, kwB,kb, vwB,vb, qG, kG, vG);
    hipLaunchKernelGGL(k_cp, dim3(nw), dim3(1024), 131072, stream,
                       qG, kG, vG, y, pwB, pb, out, part, win0);
  }
  hipLaunchKernelGGL(k3_stats, dim3(24), dim3(256), 0, stream, part, stats);
  hipLaunchKernelGGL(k_d, dim3(1024, 12, 2), dim3(256), 0, stream,
                     n2w,n2b, f1wB,f1b, f2wB,f2b_, stats, out);
}

// Round 7
// 1689.114 us; speedup vs baseline: 3.7541x; 1.1223x over previous
//
#include <hip/hip_runtime.h>
#include <hip/hip_bf16.h>

#define IMG 256
#define NPOS 65536

typedef __attribute__((ext_vector_type(8))) short short8;
typedef __attribute__((ext_vector_type(4))) float f32x4;

__device__ __forceinline__ float gelu_exact(float x){
  return 0.5f * x * (1.0f + erff(x * 0.7071067811865475f));
}

__device__ __forceinline__ short f2b(float x){
  __hip_bfloat16 hh = __float2bfloat16(x);
  short s;
  __builtin_memcpy(&s, &hh, sizeof(s));
  return s;
}

template<int NWAVES>
__device__ __forceinline__ void block_reduce2(float& s, float& s2, float* red){
  __syncthreads();  // protect red[] reuse from previous call
  #pragma unroll
  for (int off=32; off>0; off>>=1){ s += __shfl_down(s, off); s2 += __shfl_down(s2, off); }
  int lane = threadIdx.x & 63, w = threadIdx.x >> 6;
  if (lane==0){ red[w*2]=s; red[w*2+1]=s2; }
  __syncthreads();
  if (threadIdx.x==0){
    float a=0.f, bb=0.f;
    #pragma unroll
    for (int i=0;i<NWAVES;i++){ a+=red[i*2]; bb+=red[i*2+1]; }
    red[2*NWAVES]=a; red[2*NWAVES+1]=bb;
  }
  __syncthreads();
  s=red[2*NWAVES]; s2=red[2*NWAVES+1];
}

// ---------------- W_CVT: f32 -> bf16 weights, once per launch ----------------
__global__ __launch_bounds__(1024) void w_cvt(
    const float* __restrict__ w0, const float* __restrict__ w1,
    const float* __restrict__ w2, const float* __restrict__ w3,
    const float* __restrict__ w4, const float* __restrict__ w5,
    short* __restrict__ outw)
{
  const int mi = blockIdx.y;
  const float* src = mi==0?w0: mi==1?w1: mi==2?w2: mi==3?w3: mi==4?w4: w5;
  const int i = blockIdx.x*1024 + threadIdx.x;
  outw[(size_t)mi*49152 + i] = f2b(src[i]);
}

// ============ K_ABCP: per-window norm1+CPE + qkv + attention + proj ============
// 1 block per window, 1024 threads (16 waves), 128 KB dynamic LDS.
// LDS map: phase1-2: ynT bf16 [64 pos][768 ch] swizzled at byte 0..98303,
//          bufA f32 [64][65] at 98304..114943, red at 114944..115079.
// phase3: wave-private 8 KB regions at h*8192 (V^T then P, swizzled).
// phase4: O-buffer bf16 [12 g][64 n][64 ci] swizzled at 0..98303.
__global__ __launch_bounds__(1024) void k_abcp(
    const float* __restrict__ y,
    const float* __restrict__ n1w, const float* __restrict__ n1b,
    const float* __restrict__ cw,  const float* __restrict__ cb,
    const float* __restrict__ cnw, const float* __restrict__ cnb,
    const short* __restrict__ qwB, const float* __restrict__ qb,
    const short* __restrict__ kwB, const float* __restrict__ kb,
    const short* __restrict__ vwB, const float* __restrict__ vb,
    const short* __restrict__ pwB, const float* __restrict__ pb,
    short* __restrict__ qG, short* __restrict__ kG, short* __restrict__ vG,
    float* __restrict__ out, float* __restrict__ part, int win0)
{
  extern __shared__ short SM[];
  char* SMb = (char*)SM;
  float* bufA = (float*)(SMb + 98304);
  float* red  = (float*)(SMb + 114944);

  const int t = threadIdx.x;
  const int wl = blockIdx.x;
  const int win = win0 + wl;
  const int b = win>>10, W1=(win>>5)&31, W2=win&31;
  const size_t ybase = (size_t)b*768*(size_t)NPOS + (size_t)(W1*8)*IMG + (W2*8);

  // ================= Phase 1: norm1 + CPE -> LDS ynT (swizzled) =================
  for (int g=0; g<12; ++g){
    // mapping A: ch = t>>4 (64), r4 = t&15 -> pos = r4*4..+3 (float4)
    const int ch = t>>4, r4 = t&15;
    const float* yp = y + ybase + (size_t)(g*64+ch)*NPOS + (size_t)(r4>>1)*IMG + (r4&1)*4;
    float4 v0 = *(const float4*)yp;
    float vals[4] = {v0.x, v0.y, v0.z, v0.w};
    float s = 0.f, s2 = 0.f;
    #pragma unroll
    for (int kk=0;kk<4;kk++){ s += vals[kk]; s2 += vals[kk]*vals[kk]; }
    block_reduce2<16>(s,s2,red);
    float mean = s * (1.f/4096.f);
    float rstd = rsqrtf(s2*(1.f/4096.f) - mean*mean + 1e-5f);
    float nw_ = n1w[g*64+ch], nb_ = n1b[g*64+ch];
    #pragma unroll
    for (int kk=0;kk<4;kk++)
      bufA[ch*65 + r4*4 + kk] = (vals[kk]-mean)*rstd*nw_ + nb_;
    __syncthreads();

    // mapping B: sp = t&63, channels cb4 = (t>>6)*4 .. +3
    const int sp = t&63, p1 = sp>>3, p2 = sp&7;
    const int cb4 = (t>>6)*4;
    float cv[4];
    s = 0.f; s2 = 0.f;
    #pragma unroll
    for (int kk2=0;kk2<4;kk2++){
      int ch2 = cb4 + kk2;
      int c2 = g*64 + ch2;
      const float* wp = cw + c2*9;
      float acc = cb[c2];
      #pragma unroll
      for (int dy=0;dy<3;dy++){
        int yy = p1+dy-1;
        if (yy>=0 && yy<8){
          #pragma unroll
          for (int dx=0;dx<3;dx++){
            int xx = p2+dx-1;
            if (xx>=0 && xx<8) acc = fmaf(wp[dy*3+dx], bufA[ch2*65 + yy*8+xx], acc);
          }
        }
      }
      cv[kk2]=acc; s+=acc; s2+=acc*acc;
    }
    block_reduce2<16>(s,s2,red);
    float mean2 = s*(1.f/4096.f);
    float rstd2 = rsqrtf(s2*(1.f/4096.f) - mean2*mean2 + 1e-5f);
    unsigned int pk[2];
    #pragma unroll
    for (int kk2=0;kk2<4;kk2++){
      int ch2 = cb4 + kk2;
      int c2 = g*64 + ch2;
      float f = (cv[kk2]-mean2)*rstd2*cnw[c2] + cnb[c2];
      float val = bufA[ch2*65+sp] + gelu_exact(f);
      unsigned int u = (unsigned short)f2b(val);
      if (kk2&1) pk[kk2>>1] |= (u<<16); else pk[kk2>>1] = u;
    }
    // swizzled ynT write: byte = sp*1536 + (c*2 ^ ((sp&7)<<4)); 8 B aligned
    {
      int cs = g*64 + cb4;
      int bytea = sp*1536 + ((cs*2) ^ ((sp&7)<<4));
      *(uint2*)(SMb + bytea) = make_uint2(pk[0], pk[1]);
    }
    __syncthreads();
  }

  const int h = t>>6, ln = t&63;
  const int l15 = ln&15, c4 = ln>>4, kb8 = c4*8, rbase = c4*4;

  // ================= Phase 2: qkv GEMM (LDS ynT -> global qkv) =================
  for (int u = h; u < 36; u += 16){
    const int mat = (u<12)?0:((u<24)?1:2);
    const int g = u - mat*12;
    const short* WB = mat==0?qwB:(mat==1?kwB:vwB);
    const float* Bb = mat==0?qb:(mat==1?kb:vb);
    short* dst = mat==0?qG:(mat==1?kG:vG);
    short8 afr[4][2];
    float bias[4][4];
    #pragma unroll
    for (int mt2=0;mt2<4;++mt2){
      #pragma unroll
      for (int ks=0;ks<2;++ks)
        afr[mt2][ks] = *(const short8*)&WB[(size_t)(g*64+mt2*16+l15)*64 + ks*32 + kb8];
      #pragma unroll
      for (int r=0;r<4;++r)
        bias[mt2][r] = Bb[g*64 + mt2*16 + rbase + r];
    }
    #pragma unroll
    for (int nt=0;nt<4;++nt){
      const int pos = nt*16 + l15;
      short8 b0 = *(const short8*)(SMb + pos*1536 + ((g*128 +      kb8*2) ^ ((pos&7)<<4)));
      short8 b1 = *(const short8*)(SMb + pos*1536 + ((g*128 + 64 + kb8*2) ^ ((pos&7)<<4)));
      #pragma unroll
      for (int mt2=0;mt2<4;++mt2){
        f32x4 acc = {0.f,0.f,0.f,0.f};
        acc = __builtin_amdgcn_mfma_f32_16x16x32_bf16(afr[mt2][0], b0, acc, 0,0,0);
        acc = __builtin_amdgcn_mfma_f32_16x16x32_bf16(afr[mt2][1], b1, acc, 0,0,0);
        #pragma unroll
        for (int r=0;r<4;++r){
          const int hh = rbase + r;      // head
          float val = acc[r] + bias[mt2][r];
          size_t addr = ((size_t)(wl*16 + hh)*48 + 4*g + mt2)*64 + pos;
          dst[addr] = f2b(mat==0 ? val * 0.14433756729740643f : val);
        }
      }
    }
  }

  __threadfence_block();   // make same-block global qkv writes visible
  __syncthreads();         // (barrier also drains vmcnt)

  // ================= Phase 3: attention (round-5 k_cp body) =================
  const size_t hbase = (size_t)(wl*16+h)*48;
  short* R = SM + h*4096;           // wave-private 8 KB region (aliases ynT - dead)

  short8 kf[3][2], qf[3][2];
  #pragma unroll
  for (int tt=0;tt<3;++tt)
    #pragma unroll
    for (int ks=0;ks<2;++ks){
      kf[tt][ks] = *(const short8*)&kG[(hbase + 16*tt + l15)*64 + ks*32 + kb8];
      qf[tt][ks] = *(const short8*)&qG[(hbase + 16*tt + l15)*64 + ks*32 + kb8];
    }
  f32x4 Su[6];
  const int DTa[6] = {0,1,1,2,2,2};
  const int ETa[6] = {0,0,1,0,1,2};
  #pragma unroll
  for (int u=0;u<6;++u){
    f32x4 acc = {0.f,0.f,0.f,0.f};
    acc = __builtin_amdgcn_mfma_f32_16x16x32_bf16(kf[ETa[u]][0], qf[DTa[u]][0], acc, 0,0,0);
    acc = __builtin_amdgcn_mfma_f32_16x16x32_bf16(kf[ETa[u]][1], qf[DTa[u]][1], acc, 0,0,0);
    Su[u] = acc;
  }

  float inv3[3];
  #pragma unroll
  for (int dt=0;dt<3;++dt){
    const int ub = (dt==0)?0:((dt==1)?1:3);
    float m = -1e30f;
    #pragma unroll
    for (int et=0; et<=dt; ++et)
      #pragma unroll
      for (int r=0;r<4;++r){
        bool valid = (et<dt) || ((rbase + r) <= (l15|3));
        if (valid) m = fmaxf(m, Su[ub+et][r]);
      }
    m = fmaxf(m, __shfl_xor(m,16));
    m = fmaxf(m, __shfl_xor(m,32));
    float sm = 0.f;
    #pragma unroll
    for (int et=0; et<=dt; ++et)
      #pragma unroll
      for (int r=0;r<4;++r){
        bool valid = (et<dt) || ((rbase + r) <= (l15|3));
        float p = valid ? expf(Su[ub+et][r] - m) : 0.f;
        Su[ub+et][r] = p; sm += p;
      }
    sm += __shfl_xor(sm,16);
    sm += __shfl_xor(sm,32);
    inv3[dt] = 1.f/sm;
  }

  // stage vT into private region (swizzled), read PV B-frags to regs
  short8 z8 = {0,0,0,0,0,0,0,0};
  #pragma unroll
  for (int nblk=0;nblk<8;++nblk){
    short8 v8 = z8;
    if (ln < 48) v8 = *(const short8*)&vG[(hbase + ln)*64 + nblk*8];
    #pragma unroll
    for (int j=0;j<8;++j){
      int n = nblk*8 + j;
      R[n*64 + (((ln>>3) ^ (n&7))<<3) + (ln&7)] = v8[j];
    }
  }
  short8 bv[4][2];
  #pragma unroll
  for (int nt=0;nt<4;++nt){
    const int n = 16*nt + l15;
    bv[nt][0] = *(const short8*)&R[n*64 + ((c4 ^ (n&7))<<3)];
    bv[nt][1] = *(const short8*)&R[n*64 + (((4+c4) ^ (n&7))<<3)];
  }

  // overwrite region with P (zero + swizzled scatter), read A-frags
  #pragma unroll
  for (int i_=0;i_<6;++i_) *(short8*)&R[i_*512 + ln*8] = z8;
  #pragma unroll
  for (int dt=0;dt<3;++dt){
    const int ub = (dt==0)?0:((dt==1)?1:3);
    const int d = 16*dt + l15;
    #pragma unroll
    for (int et=0; et<=dt; ++et)
      #pragma unroll
      for (int r=0;r<4;++r){
        int e = 16*et + rbase + r;
        R[d*64 + (((e>>3) ^ (d&7))<<3) + (e&7)] = f2b(Su[ub+et][r]*inv3[dt]);
      }
  }
  short8 aP[4];
  const int PDT[4] = {0,1,2,2}, PKS[4] = {0,0,0,1};
  #pragma unroll
  for (int i_=0;i_<4;++i_){
    int d = 16*PDT[i_] + l15;
    int ch = PKS[i_]*4 + c4;
    aP[i_] = *(const short8*)&R[d*64 + ((ch ^ (d&7))<<3)];
  }

  __syncthreads();   // all LDS reads done; regions become O-buffer [g][n][ci]

  // PV (reg-only) + store O into group-major swizzled O-buffer
  #pragma unroll
  for (int nt=0;nt<4;++nt){
    const int n = 16*nt + l15;
    f32x4 O0 = {0.f,0.f,0.f,0.f};
    f32x4 O1 = {0.f,0.f,0.f,0.f};
    f32x4 O2 = {0.f,0.f,0.f,0.f};
    O0 = __builtin_amdgcn_mfma_f32_16x16x32_bf16(aP[0], bv[nt][0], O0, 0,0,0);
    O1 = __builtin_amdgcn_mfma_f32_16x16x32_bf16(aP[1], bv[nt][0], O1, 0,0,0);
    O2 = __builtin_amdgcn_mfma_f32_16x16x32_bf16(aP[2], bv[nt][0], O2, 0,0,0);
    O2 = __builtin_amdgcn_mfma_f32_16x16x32_bf16(aP[3], bv[nt][1], O2, 0,0,0);
    #pragma unroll
    for (int r=0;r<4;++r){
      const int swz = (((2*r + (h>>3)) ^ (n&7))<<3) + (h&7);
      SM[(c4     )*4096 + n*64 + swz] = f2b(O0[r]);
      SM[(4 + c4 )*4096 + n*64 + swz] = f2b(O1[r]);
      SM[(8 + c4 )*4096 + n*64 + swz] = f2b(O2[r]);
    }
  }

  __syncthreads();

  // ================= Phase 4: proj + residual + norm2 partials =================
  #pragma unroll 1
  for (int j=0;j<3;++j){
    const int u = h*3 + j;
    const int g = u>>2, mt = u&3;
    short8 aw[2];
    float bi[4];
    #pragma unroll
    for (int ks=0;ks<2;++ks)
      aw[ks] = *(const short8*)&pwB[(size_t)(g*64 + mt*16 + l15)*64 + ks*32 + kb8];
    #pragma unroll
    for (int r=0;r<4;++r) bi[r] = pb[g*64 + mt*16 + rbase + r];

    f32x4 acc[4] = {};
    #pragma unroll
    for (int nt=0;nt<4;++nt){
      const int n = 16*nt + l15;
      short8 b0 = *(const short8*)&SM[g*4096 + n*64 + ((c4 ^ (n&7))<<3)];
      short8 b1 = *(const short8*)&SM[g*4096 + n*64 + (((4+c4) ^ (n&7))<<3)];
      acc[nt] = __builtin_amdgcn_mfma_f32_16x16x32_bf16(aw[0], b0, acc[nt], 0,0,0);
      acc[nt] = __builtin_amdgcn_mfma_f32_16x16x32_bf16(aw[1], b1, acc[nt], 0,0,0);
    }
    float s=0.f, s2=0.f;
    #pragma unroll
    for (int nt=0;nt<4;++nt){
      const int n = 16*nt + l15;
      const size_t rowoff = ybase + (size_t)(n>>3)*IMG + (n&7);
      #pragma unroll
      for (int r=0;r<4;++r){
        int m = mt*16 + rbase + r;
        size_t ad = rowoff + (size_t)(g*64+m)*NPOS;
        float o = y[ad] + bi[r] + acc[nt][r];
        out[ad] = o;
        s += o; s2 += o*o;
      }
    }
    #pragma unroll
    for (int off=32; off>0; off>>=1){ s += __shfl_xor(s, off); s2 += __shfl_xor(s2, off); }
    if (ln==0){
      size_t idx = ((size_t)(b*12+g)*1024 + (win&1023))*4 + mt;
      part[idx*2+0]=s; part[idx*2+1]=s2;
    }
  }
}

// ---------------- K3: finalize norm2 stats (deterministic) ----------------
__global__ __launch_bounds__(256) void k3_stats(
    const float* __restrict__ part, float* __restrict__ stats)
{
  const int bg = blockIdx.x;  // 0..23
  const int t = threadIdx.x;
  float s=0.f, s2=0.f;
  #pragma unroll
  for (int j=0;j<16;++j){
    size_t idx = (size_t)bg*4096 + t*16 + j;
    s  += part[idx*2+0];
    s2 += part[idx*2+1];
  }
  __shared__ float red[10];
  block_reduce2<4>(s,s2,red);
  if (t==0){
    const float Ninv = 1.f/(64.f*65536.f);
    float mean = s*Ninv;
    float var  = s2*Ninv - mean*mean;
    stats[bg*2+0] = mean;
    stats[bg*2+1] = rsqrtf(var + 1e-5f);
  }
}

// ---------------- K_D: norm2 + f1 + gelu + f2 + residual (MFMA, in-place) ----------
__global__ __launch_bounds__(256) void k_d(
    const float* __restrict__ n2w, const float* __restrict__ n2b,
    const short* __restrict__ f1wB, const float* __restrict__ f1b,
    const short* __restrict__ f2wB, const float* __restrict__ f2bi,
    const float* __restrict__ stats, float* __restrict__ io)
{
  __shared__ short Xb[4096];
  __shared__ short Hb[4096];
  const int t = threadIdx.x;
  const int pt = blockIdx.x, g = blockIdx.y, b = blockIdx.z;
  const int bg = b*12 + g;
  const float mean = stats[bg*2+0], rstd = stats[bg*2+1];
  const size_t base = ((size_t)(b*768 + g*64))*NPOS + (size_t)pt*64;

  const int wv = t>>6, ln = t&63;
  const int l15 = ln&15, kb8 = (ln>>4)*8, rbase = (ln>>4)*4, c4 = ln>>4;
  const int n = wv*16 + l15;

  // prefetch final-residual values (store-phase mapping) — overlaps MFMA phases
  float res[16];
  #pragma unroll
  for (int mt=0;mt<4;++mt)
    #pragma unroll
    for (int r=0;r<4;++r)
      res[mt*4+r] = io[base + (size_t)(mt*16 + rbase + r)*NPOS + n];

  {
    const int pp = t>>3, posq = t&7;
    const int ch0 = pp*2;
    const float* p0 = io + base + (size_t)ch0*NPOS + posq*8;
    float4 x00 = *(const float4*)p0;
    float4 x01 = *(const float4*)(p0+4);
    const float* p1 = p0 + NPOS;
    float4 x10 = *(const float4*)p1;
    float4 x11 = *(const float4*)(p1+4);
    float A0 = rstd*n2w[g*64+ch0],   C0 = n2b[g*64+ch0]   - mean*A0;
    float A1 = rstd*n2w[g*64+ch0+1], C1 = n2b[g*64+ch0+1] - mean*A1;
    float va[8] = {x00.x,x00.y,x00.z,x00.w,x01.x,x01.y,x01.z,x01.w};
    float vb[8] = {x10.x,x10.y,x10.z,x10.w,x11.x,x11.y,x11.z,x11.w};
    #pragma unroll
    for (int j=0;j<8;++j){
      int pos = posq*8 + j;
      unsigned int u0 = (unsigned short)f2b(va[j]*A0 + C0);
      unsigned int u1 = (unsigned short)f2b(vb[j]*A1 + C1);
      *(unsigned int*)&Xb[pos*64 + (((ch0>>3) ^ (pos&7))<<3) + (ch0&7)] = u0 | (u1<<16);
    }
  }
  __syncthreads();

  short8 af[4][2];
  #pragma unroll
  for (int mt=0;mt<4;++mt)
    #pragma unroll
    for (int ks=0;ks<2;++ks)
      af[mt][ks] = *(const short8*)&f1wB[(size_t)(g*64 + mt*16 + l15)*64 + ks*32 + kb8];
  f32x4 h[4] = {};
  #pragma unroll
  for (int ks=0;ks<2;++ks){
    short8 bfr = *(const short8*)&Xb[n*64 + (((ks*4 + c4) ^ (n&7))<<3)];
    #pragma unroll
    for (int mt=0;mt<4;++mt)
      h[mt] = __builtin_amdgcn_mfma_f32_16x16x32_bf16(af[mt][ks], bfr, h[mt], 0,0,0);
  }
  #pragma unroll
  for (int mt=0;mt<4;++mt){
    #pragma unroll
    for (int rp=0;rp<4;rp+=2){
      int m = mt*16 + rbase + rp;
      float h0 = gelu_exact(h[mt][rp]   + f1b[g*64+m]);
      float h1 = gelu_exact(h[mt][rp+1] + f1b[g*64+m+1]);
      unsigned int u0 = (unsigned short)f2b(h0);
      unsigned int u1 = (unsigned short)f2b(h1);
      *(unsigned int*)&Hb[n*64 + (((m>>3) ^ (n&7))<<3) + (m&7)] = u0 | (u1<<16);
    }
  }
  __syncthreads();

  #pragma unroll
  for (int mt=0;mt<4;++mt)
    #pragma unroll
    for (int ks=0;ks<2;++ks)
      af[mt][ks] = *(const short8*)&f2wB[(size_t)(g*64 + mt*16 + l15)*64 + ks*32 + kb8];
  f32x4 o[4] = {};
  #pragma unroll
  for (int ks=0;ks<2;++ks){
    short8 bfr = *(const short8*)&Hb[n*64 + (((ks*4 + c4) ^ (n&7))<<3)];
    #pragma unroll
    for (int mt=0;mt<4;++mt)
      o[mt] = __builtin_amdgcn_mfma_f32_16x16x32_bf16(af[mt][ks], bfr, o[mt], 0,0,0);
  }
  #pragma unroll
  for (int mt=0;mt<4;++mt)
    #pragma unroll
    for (int r=0;r<4;++r){
      int m = mt*16 + rbase + r;
      io[base + (size_t)m*NPOS + n] = res[mt*4+r] + o[mt][r] + f2bi[g*64+m];
    }
}

extern "C" void kernel_launch(void* const* d_in, const int* in_sizes, int n_in,
                              void* d_out, int out_size, void* d_ws, size_t ws_size,
                              hipStream_t stream){
  const float* y    = (const float*)d_in[0];
  const float* n1w  = (const float*)d_in[1];
  const float* n1b  = (const float*)d_in[2];
  const float* cw   = (const float*)d_in[3];
  const float* cb   = (const float*)d_in[4];
  const float* cnw  = (const float*)d_in[5];
  const float* cnb  = (const float*)d_in[6];
  const float* qw   = (const float*)d_in[7];
  const float* qb   = (const float*)d_in[8];
  const float* kw   = (const float*)d_in[9];
  const float* kb   = (const float*)d_in[10];
  const float* vw   = (const float*)d_in[11];
  const float* vb   = (const float*)d_in[12];
  const float* pw   = (const float*)d_in[13];
  const float* pb   = (const float*)d_in[14];
  const float* n2w  = (const float*)d_in[15];
  const float* n2b  = (const float*)d_in[16];
  const float* f1w  = (const float*)d_in[17];
  const float* f1b  = (const float*)d_in[18];
  const float* f2w  = (const float*)d_in[19];
  const float* f2b_ = (const float*)d_in[20];
  float* out   = (float*)d_out;

  unsigned char* wsb = (unsigned char*)d_ws;
  float* part  = (float*)wsb;                 // 786432 B
  float* stats = part + 24*1024*4*2;          // 48 f32
  short* wbf   = (short*)(wsb + 786624);      // 6 * 49152 bf16
  short* qwB  = wbf;
  short* kwB  = wbf + 49152;
  short* vwB  = wbf + 2*49152;
  short* pwB  = wbf + 3*49152;
  short* f1wB = wbf + 4*49152;
  short* f2wB = wbf + 5*49152;

  // adaptive chunking: 3 buffers (q, k, v) of Y bytes each, from 2 MB offset
  int C = 32;
  {
    const int cand[6] = {1,2,4,8,16,32};
    for (int i=0;i<6;++i){
      int nw = 2048 / cand[i];
      size_t Y = (size_t)nw * 16 * 48 * 64 * 2;
      if ((size_t)(1<<21) + 3*Y <= ws_size){ C = cand[i]; break; }
    }
  }
  const int nw = 2048 / C;
  const size_t Y = (size_t)nw * 16 * 48 * 64 * 2;
  short* qG  = (short*)(wsb + (1<<21));
  short* kG  = (short*)(wsb + (1<<21) + Y);
  short* vG  = (short*)(wsb + (1<<21) + 2*Y);

  hipLaunchKernelGGL(w_cvt, dim3(48, 6), dim3(1024), 0, stream,
                     qw, kw, vw, pw, f1w, f2w, wbf);

  for (int c=0; c<C; ++c){
    int win0 = c * nw;
    hipLaunchKernelGGL(k_abcp, dim3(nw), dim3(1024), 131072, stream,
                       y, n1w,n1b, cw,cb, cnw,cnb,
                       qwB,qb, kwB,kb, vwB,vb, pwB,pb,
                       qG, kG, vG, out, part, win0);
  }
  hipLaunchKernelGGL(k3_stats, dim3(24), dim3(256), 0, stream, part, stats);
  hipLaunchKernelGGL(k_d, dim3(1024, 12, 2), dim3(256), 0, stream,
                     n2w,n2b, f1wB,f1b, f2wB,f2b_, stats, out);
}